// Round 2
// baseline (426.832 us; speedup 1.0000x reference)
//
#include <hip/hip_runtime.h>
#include <hip/hip_bf16.h>
#include <hip/hip_cooperative_groups.h>

namespace cg = cooperative_groups;

typedef __hip_bfloat16 bf16;
typedef __attribute__((ext_vector_type(8))) short bf16x8;
typedef __attribute__((ext_vector_type(4))) float f32x4;

// ---------- helpers ----------
__device__ __forceinline__ float bflo(unsigned u) { return __uint_as_float(u << 16); }
__device__ __forceinline__ float bfhi(unsigned u) { return __uint_as_float(u & 0xffff0000u); }
__device__ __forceinline__ bool probe_f32(const void* mask) {
  return *(const unsigned*)mask == 0x3F800000u;
}
__device__ __forceinline__ float ldin(const void* p, size_t i, bool f32) {
  return f32 ? ((const float*)p)[i] : (float)((const bf16*)p)[i];
}

struct MegaArgs {
  const void *q, *spike, *mask, *tl;
  const void *w0, *w1, *w2, *w3, *w4, *w5;
  const void *b0, *b1, *b2, *b3, *b4, *b5, *g, *be;
  const void *anchors, *lsig;
  bf16* Wall; float* biasF; bf16* q_rot; float* qn;
  bf16* MQ; float* h_part; float* pd_part; float* Kh; float* Vh;
  bf16* attn_o; bf16* msg_a; void* out;
};

// ---------- phase bodies (identical logic to the verified 6-kernel version) ----------

__device__ __forceinline__ void prologue_job(const MegaArgs& A, bool f32, int blk, int t) {
  if (blk < 1536) {
    const int compT[4][4] = {{0,1,2,3},{1,0,3,2},{2,3,0,1},{3,2,1,0}};
    const float signT[4][4] = {{1.f,-1.f,-1.f,-1.f},{1.f,1.f,-1.f,1.f},{1.f,1.f,1.f,-1.f},{1.f,-1.f,1.f,1.f}};
    int E = blk * 1024 + t * 4;
    int wi = E >> 18;
    const void* src = wi == 0 ? A.w0 : wi == 1 ? A.w1 : wi == 2 ? A.w2
                    : wi == 3 ? A.w3 : wi == 4 ? A.w4 : A.w5;
    bf16 ov[4];
    #pragma unroll
    for (int j = 0; j < 4; ++j) {
      int e = (E + j) & 262143;
      int o = e >> 9, kk = e & 511;
      int ro = o >> 7, a = o & 127, co = kk >> 7, b2 = kk & 127;
      ov[j] = (bf16)(ldin(src, compT[ro][co] * 16384 + a * 128 + b2, f32) * signT[ro][co]);
    }
    *(uint2*)(A.Wall + E) = *(const uint2*)ov;
  } else if (blk < 1544) {
    int b = blk - 1536;
    const void* src = b == 0 ? A.b0 : b == 1 ? A.b1 : b == 2 ? A.b2 : b == 3 ? A.b3
                    : b == 4 ? A.b4 : b == 5 ? A.b5 : b == 6 ? A.g : A.be;
    A.biasF[b * 512 + t] = ldin(src, t, f32);
    A.biasF[b * 512 + 256 + t] = ldin(src, 256 + t, f32);
  } else {
    int row = (blk - 1544) * 2 + (t >> 7);
    int l = t & 127;
    float tl = ldin(A.tl, 0, f32);
    float tmax = 1.5707963267948966f / (1.0f + __expf(-tl));
    float th = tmax * ldin(A.spike, row, f32);
    float c = cosf(th), s = sinf(th);
    size_t base = (size_t)row * 512;
    float a = ldin(A.q, base + l, f32), b = ldin(A.q, base + 128 + l, f32);
    float cc = ldin(A.q, base + 256 + l, f32), d = ldin(A.q, base + 384 + l, f32);
    float r0 = c * a - s * d;
    float r1 = c * b - s * cc;
    float r2 = c * cc + s * b;
    float r3 = c * d + s * a;
    bf16* orow = A.q_rot + base;
    orow[l] = (bf16)r0; orow[128 + l] = (bf16)r1; orow[256 + l] = (bf16)r2; orow[384 + l] = (bf16)r3;
    A.qn[(size_t)row * 128 + l] = r0 * r0 + r1 * r1 + r2 * r2 + r3 * r3;
  }
}

// B-tile [64 rows x 512 k] -> fragment-major LDS
__device__ __forceinline__ void stage_B64(const bf16* __restrict__ Bw, int n0, char* Bs, int t) {
  int r = t & 63, cb = (t >> 6) * 16;
  const bf16* src = Bw + (size_t)(n0 + r) * 512;
  #pragma unroll
  for (int i = 0; i < 16; ++i) {
    int c = cb + i;
    int off = (c >> 2) * 4096 + (r >> 4) * 1024 + (((c & 3) * 16 + (r & 15)) * 16);
    *(uint4*)(Bs + off) = *(const uint4*)(src + c * 8);
  }
}

__device__ __forceinline__ void gemm1_tile(
    const bf16* __restrict__ Aq, const bf16* __restrict__ Bw,
    const float* __restrict__ bias0, const float* __restrict__ bias1,
    bf16* __restrict__ MQ, char* smem, int g, int t) {
  char* Bs = smem;
  const int wave = t >> 6, lane = t & 63;
  const int quad = lane >> 4, l16 = lane & 15;
  const int m0 = (g & 31) * 256, n0 = (g >> 5) * 64;
  __syncthreads();
  stage_B64(Bw, n0, Bs, t);
  __syncthreads();
  const int mbase = m0 + wave * 64;
  f32x4 acc[4][4] = {};
  bf16x8 areg[2][4], breg[2][4];
  #pragma unroll
  for (int mt = 0; mt < 4; ++mt)
    areg[0][mt] = *(const bf16x8*)(Aq + (size_t)(mbase + mt * 16 + l16) * 512 + quad * 8);
  #pragma unroll
  for (int nt = 0; nt < 4; ++nt)
    breg[0][nt] = *(const bf16x8*)(Bs + nt * 1024 + lane * 16);
  #pragma unroll
  for (int kk = 0; kk < 16; ++kk) {
    const int cur = kk & 1, nxt = cur ^ 1;
    if (kk < 15) {
      const int k2 = (kk + 1) * 32;
      #pragma unroll
      for (int mt = 0; mt < 4; ++mt)
        areg[nxt][mt] = *(const bf16x8*)(Aq + (size_t)(mbase + mt * 16 + l16) * 512 + k2 + quad * 8);
      #pragma unroll
      for (int nt = 0; nt < 4; ++nt)
        breg[nxt][nt] = *(const bf16x8*)(Bs + (kk + 1) * 4096 + nt * 1024 + lane * 16);
    }
    #pragma unroll
    for (int mt = 0; mt < 4; ++mt)
      #pragma unroll
      for (int nt = 0; nt < 4; ++nt)
        acc[mt][nt] = __builtin_amdgcn_mfma_f32_16x16x32_bf16(areg[cur][mt], breg[cur][nt],
                                                              acc[mt][nt], 0, 0, 0);
  }
  #pragma unroll
  for (int nt = 0; nt < 4; ++nt) {
    int col = n0 + nt * 16 + l16;
    float bv = col < 512 ? bias0[col] : bias1[col - 512];
    #pragma unroll
    for (int mt = 0; mt < 4; ++mt) {
      int rb = mbase + mt * 16 + quad * 4;
      #pragma unroll
      for (int r = 0; r < 4; ++r)
        MQ[(size_t)(rb + r) * 1024 + col] = (bf16)(acc[mt][nt][r] + bv);
    }
  }
}

__device__ __forceinline__ void dist_job(const MegaArgs& Ar, bool f32, char* smem, int bb, int t) {
  bf16*  qr   = (bf16*)smem;                  // 65536 B
  float* an   = (float*)(smem + 65536);       // 8192 B
  float* sInc = (float*)(smem + 73728);       // 4096 B
  float* rs   = (float*)(smem + 77824);       // 64 B
  float* pd   = (float*)(smem + 77888);       // 64 B
  int b = bb >> 4, nc = bb & 15;
  __syncthreads();
  {
    const uint4* src = (const uint4*)((const bf16*)Ar.q_rot + ((size_t)b * 1024 + nc * 64) * 512);
    uint4* dst = (uint4*)qr;
    #pragma unroll
    for (int i = 0; i < 16; ++i) dst[t + i * 256] = src[t + i * 256];
  }
  for (int i = t; i < 2048; i += 256) {
    int k = i >> 7, l = i & 127;
    float a0 = ldin(Ar.anchors, k * 512 + l, f32);
    float a1 = ldin(Ar.anchors, k * 512 + 128 + l, f32);
    float a2 = ldin(Ar.anchors, k * 512 + 256 + l, f32);
    float a3 = ldin(Ar.anchors, k * 512 + 384 + l, f32);
    an[i] = a0 * a0 + a1 * a1 + a2 * a2 + a3 * a3;
  }
  if (t < 16) {
    float ls = ldin(Ar.lsig, t, f32);
    float ssq = __expf(ls); ssq = fmaxf(ssq * ssq, 1e-6f);
    rs[t] = -1.0f / ssq;
    pd[t] = 0.0f;
  }
  __syncthreads();
  {
    int rl = t >> 2, part = t & 3;
    int n = nc * 64 + rl;
    const float* qrow = Ar.qn + ((size_t)b * 1024 + n) * 128 + part * 32;
    f32x4 q4[8];
    #pragma unroll
    for (int i = 0; i < 8; ++i) q4[i] = *(const f32x4*)(qrow + i * 4);
    float sc[16] = {};
    #pragma unroll
    for (int i = 0; i < 8; ++i) {
      #pragma unroll
      for (int k = 0; k < 16; ++k) {
        f32x4 av = *(const f32x4*)(an + k * 128 + part * 32 + i * 4);
        sc[k] += q4[i][0] * av[0] + q4[i][1] * av[1] + q4[i][2] * av[2] + q4[i][3] * av[3];
      }
    }
    #pragma unroll
    for (int k = 0; k < 16; ++k) {
      sc[k] += __shfl_xor(sc[k], 1, 64);
      sc[k] += __shfl_xor(sc[k], 2, 64);
    }
    if (part == 0) {
      float mval = ldin(Ar.mask, b * 1024 + n, f32);
      #pragma unroll
      for (int k = 0; k < 16; ++k) {
        float inc = __expf(sc[k] * rs[k]) * mval;
        sInc[k * 64 + rl] = inc;
        atomicAdd(&pd[k], inc);
      }
    }
  }
  __syncthreads();
  {
    float acc0[16] = {}, acc1[16] = {};
    for (int nn = 0; nn < 64; ++nn) {
      float v0 = (float)qr[nn * 512 + t];
      float v1 = (float)qr[nn * 512 + 256 + t];
      #pragma unroll
      for (int k = 0; k < 16; ++k) {
        float p = sInc[k * 64 + nn];
        acc0[k] += p * v0;
        acc1[k] += p * v1;
      }
    }
    #pragma unroll
    for (int k = 0; k < 16; ++k) {
      size_t base = ((size_t)(b * 16 + k) * 16 + nc) * 512;
      Ar.h_part[base + t] = acc0[k];
      Ar.h_part[base + 256 + t] = acc1[k];
    }
  }
  if (t < 16) Ar.pd_part[((size_t)(b * 16 + t)) * 16 + nc] = pd[t];
}

__device__ __forceinline__ void qlin_job(const MegaArgs& A, char* smem, int job, int t) {
  float* xs = (float*)smem;
  float* ys = (float*)(smem + 2048);
  const bf16* Wa = A.Wall + 3 * 262144;
  const bf16* Wk = A.Wall + 4 * 262144;
  const bf16* Wv = A.Wall + 5 * 262144;
  const float* ba = A.biasF + 1536;
  const float* bk = A.biasF + 2048;
  const float* bv = A.biasF + 2560;
  int row = job >> 1, half = job & 1;
  __syncthreads();
  float dsum = 0.0f;
  #pragma unroll
  for (int nc = 0; nc < 16; ++nc) dsum += A.pd_part[row * 16 + nc];
  float dinv = 1.0f / fmaxf(dsum, 1e-6f);
  #pragma unroll
  for (int j = 0; j < 2; ++j) {
    int d = j * 256 + t;
    float hv = 0.0f;
    #pragma unroll
    for (int nc = 0; nc < 16; ++nc) hv += A.h_part[(size_t)row * 8192 + nc * 512 + d];
    xs[d] = hv * dinv;
  }
  __syncthreads();
  #pragma unroll
  for (int j = 0; j < 2; ++j) {
    int o = j * 256 + t;
    const uint4* wr = (const uint4*)(Wa + (size_t)o * 512);
    float acc = ba[o];
    #pragma unroll 4
    for (int c = 0; c < 64; ++c) {
      uint4 u = wr[c];
      const float* xp = xs + c * 8;
      acc += xp[0] * bflo(u.x) + xp[1] * bfhi(u.x)
           + xp[2] * bflo(u.y) + xp[3] * bfhi(u.y)
           + xp[4] * bflo(u.z) + xp[5] * bfhi(u.z)
           + xp[6] * bflo(u.w) + xp[7] * bfhi(u.w);
    }
    ys[o] = acc;
  }
  __syncthreads();
  {
    int o = half * 256 + t;
    const uint4* wk = (const uint4*)(Wk + (size_t)o * 512);
    const uint4* wv = (const uint4*)(Wv + (size_t)o * 512);
    float ak = bk[o], av = bv[o];
    #pragma unroll 2
    for (int c = 0; c < 64; ++c) {
      uint4 uk = wk[c], uv = wv[c];
      const float* xp = ys + c * 8;
      ak += xp[0] * bflo(uk.x) + xp[1] * bfhi(uk.x)
          + xp[2] * bflo(uk.y) + xp[3] * bfhi(uk.y)
          + xp[4] * bflo(uk.z) + xp[5] * bfhi(uk.z)
          + xp[6] * bflo(uk.w) + xp[7] * bfhi(uk.w);
      av += xp[0] * bflo(uv.x) + xp[1] * bfhi(uv.x)
          + xp[2] * bflo(uv.y) + xp[3] * bfhi(uv.y)
          + xp[4] * bflo(uv.z) + xp[5] * bfhi(uv.z)
          + xp[6] * bflo(uv.w) + xp[7] * bfhi(uv.w);
    }
    A.Kh[(size_t)row * 512 + o] = ak;
    A.Vh[(size_t)row * 512 + o] = av;
  }
}

__device__ __forceinline__ void attn_job(const MegaArgs& A, char* smem, int job, int t) {
  float* KV = (float*)smem;                 // 8*1092*4 = 34944 B
  float* P  = (float*)(smem + 34944);       // 16*132*4 = 8448 B
  const int rowbase = job * 16;
  const int b = rowbase >> 10;
  __syncthreads();
  for (int i = t; i < 8192; i += 256) {
    int k = i >> 9, d = i & 511, h = d >> 6, dd = d & 63;
    KV[h * 1092 + k * 68 + dd] = A.Kh[(size_t)b * 8192 + i];
  }
  __syncthreads();
  {
    const int r = t >> 4, h = (t >> 1) & 7, hf = t & 1;
    const int grow = rowbase + r;
    const uint4* qp = (const uint4*)(A.MQ + (size_t)grow * 1024 + 512 + h * 64 + hf * 32);
    float q[32];
    #pragma unroll
    for (int i = 0; i < 4; ++i) {
      uint4 u = qp[i];
      q[i * 8 + 0] = bflo(u.x); q[i * 8 + 1] = bfhi(u.x);
      q[i * 8 + 2] = bflo(u.y); q[i * 8 + 3] = bfhi(u.y);
      q[i * 8 + 4] = bflo(u.z); q[i * 8 + 5] = bfhi(u.z);
      q[i * 8 + 6] = bflo(u.w); q[i * 8 + 7] = bfhi(u.w);
    }
    float sc[16];
    #pragma unroll
    for (int k = 0; k < 16; ++k) {
      float s = 0.0f;
      #pragma unroll
      for (int d4 = 0; d4 < 8; ++d4) {
        f32x4 kv = *(const f32x4*)(KV + h * 1092 + k * 68 + hf * 32 + d4 * 4);
        s += q[d4 * 4 + 0] * kv[0] + q[d4 * 4 + 1] * kv[1]
           + q[d4 * 4 + 2] * kv[2] + q[d4 * 4 + 3] * kv[3];
      }
      sc[k] = s;
    }
    #pragma unroll
    for (int k = 0; k < 16; ++k) sc[k] += __shfl_xor(sc[k], 1, 64);
    if (hf == 0) {
      #pragma unroll
      for (int k = 0; k < 16; ++k) sc[k] *= 0.125f;
      float m = sc[0];
      #pragma unroll
      for (int k = 1; k < 16; ++k) m = fmaxf(m, sc[k]);
      float ssum = 0.0f;
      #pragma unroll
      for (int k = 0; k < 16; ++k) { sc[k] = __expf(sc[k] - m); ssum += sc[k]; }
      float inv = 1.0f / ssum;
      #pragma unroll
      for (int k = 0; k < 16; ++k) P[r * 132 + h * 16 + k] = sc[k] * inv;
    }
  }
  __syncthreads();
  for (int i = t; i < 8192; i += 256) {
    int k = i >> 9, d = i & 511, h = d >> 6, dd = d & 63;
    KV[h * 1092 + k * 68 + dd] = A.Vh[(size_t)b * 8192 + i];
  }
  __syncthreads();
  {
    const int r = t >> 4, dg = t & 15;
    #pragma unroll
    for (int h = 0; h < 8; ++h) {
      float a0 = 0, a1 = 0, a2 = 0, a3 = 0;
      #pragma unroll
      for (int k = 0; k < 16; ++k) {
        float p = P[r * 132 + h * 16 + k];
        f32x4 va = *(const f32x4*)(KV + h * 1092 + k * 68 + dg * 4);
        a0 += p * va[0]; a1 += p * va[1]; a2 += p * va[2]; a3 += p * va[3];
      }
      bf16 ov[4] = {(bf16)a0, (bf16)a1, (bf16)a2, (bf16)a3};
      *(uint2*)(A.attn_o + (size_t)(rowbase + r) * 512 + h * 64 + dg * 4) = *(const uint2*)ov;
    }
  }
}

__device__ __forceinline__ void gemm2_tile(
    const bf16* __restrict__ Ai, const bf16* __restrict__ Bw,
    const float* __restrict__ biasO, bf16* __restrict__ msg_a, char* smem, int job, int t) {
  char* Bs = smem;
  const int wave = t >> 6, lane = t & 63;
  const int quad = lane >> 4, l16 = lane & 15;
  const int m0 = (job & 63) * 128, n0 = (job >> 6) * 64;
  __syncthreads();
  stage_B64(Bw, n0, Bs, t);
  __syncthreads();
  const int mbase = m0 + wave * 32;
  f32x4 acc[2][4] = {};
  bf16x8 areg[2][2], breg[2][4];
  #pragma unroll
  for (int mt = 0; mt < 2; ++mt)
    areg[0][mt] = *(const bf16x8*)(Ai + (size_t)(mbase + mt * 16 + l16) * 512 + quad * 8);
  #pragma unroll
  for (int nt = 0; nt < 4; ++nt)
    breg[0][nt] = *(const bf16x8*)(Bs + nt * 1024 + lane * 16);
  #pragma unroll
  for (int kk = 0; kk < 16; ++kk) {
    const int cur = kk & 1, nxt = cur ^ 1;
    if (kk < 15) {
      const int k2 = (kk + 1) * 32;
      #pragma unroll
      for (int mt = 0; mt < 2; ++mt)
        areg[nxt][mt] = *(const bf16x8*)(Ai + (size_t)(mbase + mt * 16 + l16) * 512 + k2 + quad * 8);
      #pragma unroll
      for (int nt = 0; nt < 4; ++nt)
        breg[nxt][nt] = *(const bf16x8*)(Bs + (kk + 1) * 4096 + nt * 1024 + lane * 16);
    }
    #pragma unroll
    for (int mt = 0; mt < 2; ++mt)
      #pragma unroll
      for (int nt = 0; nt < 4; ++nt)
        acc[mt][nt] = __builtin_amdgcn_mfma_f32_16x16x32_bf16(areg[cur][mt], breg[cur][nt],
                                                              acc[mt][nt], 0, 0, 0);
  }
  #pragma unroll
  for (int nt = 0; nt < 4; ++nt) {
    int col = n0 + nt * 16 + l16;
    float bv = biasO[col];
    #pragma unroll
    for (int mt = 0; mt < 2; ++mt) {
      int rb = mbase + mt * 16 + quad * 4;
      #pragma unroll
      for (int r = 0; r < 4; ++r)
        msg_a[(size_t)(rb + r) * 512 + col] = (bf16)(acc[mt][nt][r] + bv);
    }
  }
}

__device__ __forceinline__ void ln_job(const MegaArgs& A, bool f32, int job, int t) {
  int row = job * 2 + (t >> 7);
  int l = t & 127;
  int e0 = l * 4;
  const float* gamF = A.biasF + 3072;
  float x[4];
  {
    uint2 um = *(const uint2*)(A.MQ + (size_t)row * 1024 + e0);
    uint2 ua = *(const uint2*)(A.msg_a + (size_t)row * 512 + e0);
    float qv[4];
    if (f32) {
      f32x4 qq = *(const f32x4*)((const float*)A.q + (size_t)row * 512 + e0);
      qv[0] = qq[0]; qv[1] = qq[1]; qv[2] = qq[2]; qv[3] = qq[3];
    } else {
      uint2 uq = *(const uint2*)((const bf16*)A.q + (size_t)row * 512 + e0);
      qv[0] = bflo(uq.x); qv[1] = bfhi(uq.x); qv[2] = bflo(uq.y); qv[3] = bfhi(uq.y);
    }
    x[0] = qv[0] + bflo(um.x) + bflo(ua.x);
    x[1] = qv[1] + bfhi(um.x) + bfhi(ua.x);
    x[2] = qv[2] + bflo(um.y) + bflo(ua.y);
    x[3] = qv[3] + bfhi(um.y) + bfhi(ua.y);
  }
  float s = x[0] + x[1] + x[2] + x[3];
  float s2 = x[0] * x[0] + x[1] * x[1] + x[2] * x[2] + x[3] * x[3];
  #pragma unroll
  for (int off = 1; off <= 16; off <<= 1) {
    s  += __shfl_xor(s, off, 64);
    s2 += __shfl_xor(s2, off, 64);
  }
  float m = s * (1.0f / 128.0f);
  float rinv = rsqrtf(s2 * (1.0f / 128.0f) - m * m + 1e-5f);
  f32x4 ga = *(const f32x4*)(gamF + e0);
  f32x4 be = *(const f32x4*)(gamF + 512 + e0);
  float y[4];
  #pragma unroll
  for (int j = 0; j < 4; ++j) y[j] = (x[j] - m) * rinv * ga[j] + be[j];
  if (f32) {
    f32x4 ov = {y[0], y[1], y[2], y[3]};
    *(f32x4*)((float*)A.out + (size_t)row * 512 + e0) = ov;
  } else {
    bf16 ov[4] = {(bf16)y[0], (bf16)y[1], (bf16)y[2], (bf16)y[3]};
    *(uint2*)((bf16*)A.out + (size_t)row * 512 + e0) = *(const uint2*)ov;
  }
}

// ---------- the fused cooperative kernel ----------
__global__ __launch_bounds__(256, 2) void mega(MegaArgs A) {
  __shared__ char smem[77952];
  cg::grid_group grid = cg::this_grid();
  const int nb = (int)gridDim.x;
  const int gid = (int)blockIdx.x;
  const int t = (int)threadIdx.x;
  const bool f32 = probe_f32(A.mask);

  // Phase A: prologue (pack W, biases, spike rotation)
  for (int blk = gid; blk < 5640; blk += nb) prologue_job(A, f32, blk, t);
  grid.sync();

  // Phase B: gemm1 (512 tiles) + dist (128 jobs)
  for (int g = gid; g < 512; g += nb)
    gemm1_tile(A.q_rot, A.Wall, A.biasF, A.biasF + 512, A.MQ, smem, g, t);
  for (int bb = gid; bb < 128; bb += nb) dist_job(A, f32, smem, bb, t);
  grid.sync();

  // Phase C: aggregate + aggr/K/V projections
  for (int job = gid; job < 256; job += nb) qlin_job(A, smem, job, t);
  grid.sync();

  // Phase D: attention
  for (int job = gid; job < 512; job += nb) attn_job(A, smem, job, t);
  grid.sync();

  // Phase E: gemm2 (msg_a)
  for (int job = gid; job < 512; job += nb)
    gemm2_tile(A.attn_o, A.Wall + 2 * 262144, A.biasF + 1024, A.msg_a, smem, job, t);
  grid.sync();

  // Phase F: residual + quaternion LayerNorm
  for (int job = gid; job < 4096; job += nb) ln_job(A, f32, job, t);
}

// ---------- fallback: original six kernels (used only if cooperative launch is refused) ----------
__global__ __launch_bounds__(256) void k_prologue(MegaArgs A) {
  bool f32 = probe_f32(A.mask);
  prologue_job(A, f32, blockIdx.x, threadIdx.x);
}
__global__ __launch_bounds__(256, 2) void k_gemm_dist(MegaArgs A) {
  __shared__ char smem[77952];
  bool f32 = probe_f32(A.mask);
  if (blockIdx.x >= 128)
    gemm1_tile(A.q_rot, A.Wall, A.biasF, A.biasF + 512, A.MQ, smem, blockIdx.x - 128, threadIdx.x);
  else
    dist_job(A, f32, smem, blockIdx.x, threadIdx.x);
}
__global__ __launch_bounds__(256) void k_qlin(MegaArgs A) {
  __shared__ char smem[4096];
  qlin_job(A, smem, blockIdx.x, threadIdx.x);
}
__global__ __launch_bounds__(256) void k_attn(MegaArgs A) {
  __shared__ char smem[43392];
  attn_job(A, smem, blockIdx.x, threadIdx.x);
}
__global__ __launch_bounds__(256, 2) void k_gemm2(MegaArgs A) {
  __shared__ char smem[65536];
  gemm2_tile(A.attn_o, A.Wall + 2 * 262144, A.biasF + 1024, A.msg_a, smem, blockIdx.x, threadIdx.x);
}
__global__ __launch_bounds__(256) void k_ln(MegaArgs A) {
  bool f32 = probe_f32(A.mask);
  ln_job(A, f32, blockIdx.x, threadIdx.x);
}

// ---------- launch ----------
extern "C" void kernel_launch(void* const* d_in, const int* in_sizes, int n_in,
                              void* d_out, int out_size, void* d_ws, size_t ws_size,
                              hipStream_t stream) {
  (void)in_sizes; (void)n_in; (void)out_size; (void)ws_size;
  char* ws = (char*)d_ws;
  MegaArgs h;
  h.q = d_in[0];  h.spike = d_in[1]; h.mask = d_in[2]; h.tl = d_in[3];
  h.w0 = d_in[4]; h.b0 = d_in[5];
  h.anchors = d_in[6]; h.lsig = d_in[7];
  h.w3 = d_in[8]; h.b3 = d_in[9];     // w_aggr -> slot 3
  h.w1 = d_in[10]; h.b1 = d_in[11];   // w_q    -> slot 1
  h.w4 = d_in[12]; h.b4 = d_in[13];   // w_k    -> slot 4
  h.w5 = d_in[14]; h.b5 = d_in[15];   // w_v    -> slot 5
  h.w2 = d_in[16]; h.b2 = d_in[17];   // w_o    -> slot 2
  h.g = d_in[18]; h.be = d_in[19];
  h.Wall    = (bf16*)(ws + 0);
  h.q_rot   = (bf16*)(ws + 3145728);
  h.qn      = (float*)(ws + 11534336);
  h.MQ      = (bf16*)(ws + 15728640);
  h.h_part  = (float*)(ws + 32505856);
  h.pd_part = (float*)(ws + 36700160);
  h.Kh      = (float*)(ws + 36708352);
  h.Vh      = (float*)(ws + 36970496);
  h.attn_o  = (bf16*)(ws + 37232640);
  h.msg_a   = (bf16*)(ws + 45621248);
  h.biasF   = (float*)(ws + 54009856);
  h.out     = d_out;

  int maxB = 0;
  if (hipOccupancyMaxActiveBlocksPerMultiprocessor(&maxB, (const void*)mega, 256, 0) != hipSuccess)
    maxB = 0;
  if (maxB < 1) maxB = 1;
  int grid = maxB * 256;
  if (grid > 512) grid = 512;

  void* params[1] = { (void*)&h };
  hipError_t err = hipLaunchCooperativeKernel((const void*)mega, dim3(grid), dim3(256),
                                              params, 0, stream);
  if (err != hipSuccess) {
    // fallback: original six-kernel pipeline
    k_prologue<<<5640, 256, 0, stream>>>(h);
    k_gemm_dist<<<640, 256, 0, stream>>>(h);
    k_qlin<<<256, 256, 0, stream>>>(h);
    k_attn<<<512, 256, 0, stream>>>(h);
    k_gemm2<<<512, 256, 0, stream>>>(h);
    k_ln<<<4096, 256, 0, stream>>>(h);
  }
}

// Round 3
// 227.791 us; speedup vs baseline: 1.8738x; 1.8738x over previous
//
#include <hip/hip_runtime.h>
#include <hip/hip_bf16.h>

typedef __hip_bfloat16 bf16;
typedef __attribute__((ext_vector_type(8))) short bf16x8;
typedef __attribute__((ext_vector_type(4))) float f32x4;

// ---------- helpers ----------
__device__ __forceinline__ float bflo(unsigned u) { return __uint_as_float(u << 16); }
__device__ __forceinline__ float bfhi(unsigned u) { return __uint_as_float(u & 0xffff0000u); }
__device__ __forceinline__ bool probe_f32(const void* mask) {
  return *(const unsigned*)mask == 0x3F800000u;
}
__device__ __forceinline__ float ldin(const void* p, size_t i, bool f32) {
  return f32 ? ((const float*)p)[i] : (float)((const bf16*)p)[i];
}

// Fragment-major pack layout (global): for global row g (0..3071), col k (0..511):
//   chunk = g>>6 (64-row chunk, 65536 B each), r = g&63, c = k>>3 (16B block)
//   byte off = chunk*65536 + (c>>2)*4096 + (r>>4)*1024 + ((c&3)*16 + (r&15))*16 + (k&7)*2
// This is exactly the layout the old stage_B64 produced in LDS, so MFMA fragment
// reads are `base + kk*4096 + nt*1024 + lane*16` — coalesced 16B/lane.

// ---------- 1. prologue: pack_w (fragment-major) + biases + spike rotation ----------
__global__ __launch_bounds__(256) void prologue(
    const void* w0, const void* w1, const void* w2, const void* w3,
    const void* w4, const void* w5,
    const void* b0, const void* b1, const void* b2, const void* b3,
    const void* b4, const void* b5, const void* g_, const void* be,
    const void* q, const void* spike, const void* theta_logit, const void* mask,
    bf16* __restrict__ Wall, float* __restrict__ biasF,
    bf16* __restrict__ q_rot, float* __restrict__ qn) {
  bool f32 = probe_f32(mask);
  int blk = blockIdx.x, t = threadIdx.x;
  if (blk < 1536) {
    const int compT[4][4] = {{0,1,2,3},{1,0,3,2},{2,3,0,1},{3,2,1,0}};
    const float signT[4][4] = {{1.f,-1.f,-1.f,-1.f},{1.f,1.f,-1.f,1.f},{1.f,1.f,1.f,-1.f},{1.f,-1.f,1.f,1.f}};
    int E = blk * 1024 + t * 4;
    int g = E >> 9;            // global packed row 0..3071
    int wi = g >> 9;           // matrix index 0..5
    int o = g & 511;           // row within matrix
    int k0 = E & 511;          // col (multiple of 4)
    const void* src = wi == 0 ? w0 : wi == 1 ? w1 : wi == 2 ? w2 : wi == 3 ? w3 : wi == 4 ? w4 : w5;
    int ro = o >> 7, a = o & 127, co = k0 >> 7;
    int comp = compT[ro][co];
    float sgn = signT[ro][co];
    bf16 ov[4];
    #pragma unroll
    for (int j = 0; j < 4; ++j) {
      int b2 = (k0 & 127) + j;
      ov[j] = (bf16)(ldin(src, comp * 16384 + a * 128 + b2, f32) * sgn);
    }
    int r = g & 63, c = k0 >> 3;
    size_t off = (size_t)(g >> 6) * 65536 + (size_t)((c >> 2) * 4096 + (r >> 4) * 1024
               + ((c & 3) * 16 + (r & 15)) * 16 + (k0 & 7) * 2);
    *(uint2*)((char*)Wall + off) = *(const uint2*)ov;
  } else if (blk < 1544) {
    int b = blk - 1536;
    const void* src = b == 0 ? b0 : b == 1 ? b1 : b == 2 ? b2 : b == 3 ? b3
                    : b == 4 ? b4 : b == 5 ? b5 : b == 6 ? g_ : be;
    biasF[b * 512 + t] = ldin(src, t, f32);
    biasF[b * 512 + 256 + t] = ldin(src, 256 + t, f32);
  } else {
    int row = (blk - 1544) * 2 + (t >> 7);
    int l = t & 127;
    float tl = ldin(theta_logit, 0, f32);
    float tmax = 1.5707963267948966f / (1.0f + __expf(-tl));
    float th = tmax * ldin(spike, row, f32);
    float c = cosf(th), s = sinf(th);
    size_t base = (size_t)row * 512;
    float a = ldin(q, base + l, f32), b = ldin(q, base + 128 + l, f32);
    float cc = ldin(q, base + 256 + l, f32), d = ldin(q, base + 384 + l, f32);
    float r0 = c * a - s * d;
    float r1 = c * b - s * cc;
    float r2 = c * cc + s * b;
    float r3 = c * d + s * a;
    bf16* orow = q_rot + base;
    orow[l] = (bf16)r0; orow[128 + l] = (bf16)r1; orow[256 + l] = (bf16)r2; orow[384 + l] = (bf16)r3;
    qn[(size_t)row * 128 + l] = r0 * r0 + r1 * r1 + r2 * r2 + r3 * r3;
  }
}

// ---------- staging: now a straight coalesced 64KB copy (Wall already fragment-major) ----------
__device__ __forceinline__ void stage_B64(const bf16* __restrict__ Bw, int n0, char* Bs, int t) {
  const char* src = (const char*)Bw + (size_t)(n0 >> 6) * 65536;
  #pragma unroll
  for (int i = 0; i < 16; ++i)
    *(uint4*)(Bs + t * 16 + i * 4096) = *(const uint4*)(src + t * 16 + i * 4096);
}

// ---------- 2. FUSED dist_h + gemm1 ----------
__global__ __launch_bounds__(256, 2) void gemm_dist(
    const bf16* __restrict__ A, const bf16* __restrict__ Bw,
    const float* __restrict__ bias0, const float* __restrict__ bias1,
    bf16* __restrict__ MQ,
    const float* __restrict__ qn, const void* anchors, const void* lsig,
    const void* mask, float* __restrict__ h_part, float* __restrict__ pd_part) {
  __shared__ char smem[77952];
  const int t = threadIdx.x;
  if (blockIdx.x >= 128) {
    char* Bs = smem;
    const int g = blockIdx.x - 128;
    const int wave = t >> 6, lane = t & 63;
    const int quad = lane >> 4, l16 = lane & 15;
    const int m0 = (g & 31) * 256, n0 = (g >> 5) * 64;
    stage_B64(Bw, n0, Bs, t);
    __syncthreads();
    const int mbase = m0 + wave * 64;
    f32x4 acc[4][4] = {};
    bf16x8 areg[2][4], breg[2][4];
    #pragma unroll
    for (int mt = 0; mt < 4; ++mt)
      areg[0][mt] = *(const bf16x8*)(A + (size_t)(mbase + mt * 16 + l16) * 512 + quad * 8);
    #pragma unroll
    for (int nt = 0; nt < 4; ++nt)
      breg[0][nt] = *(const bf16x8*)(Bs + nt * 1024 + lane * 16);
    #pragma unroll
    for (int kk = 0; kk < 16; ++kk) {
      const int cur = kk & 1, nxt = cur ^ 1;
      if (kk < 15) {
        const int k2 = (kk + 1) * 32;
        #pragma unroll
        for (int mt = 0; mt < 4; ++mt)
          areg[nxt][mt] = *(const bf16x8*)(A + (size_t)(mbase + mt * 16 + l16) * 512 + k2 + quad * 8);
        #pragma unroll
        for (int nt = 0; nt < 4; ++nt)
          breg[nxt][nt] = *(const bf16x8*)(Bs + (kk + 1) * 4096 + nt * 1024 + lane * 16);
      }
      #pragma unroll
      for (int mt = 0; mt < 4; ++mt)
        #pragma unroll
        for (int nt = 0; nt < 4; ++nt)
          acc[mt][nt] = __builtin_amdgcn_mfma_f32_16x16x32_bf16(areg[cur][mt], breg[cur][nt],
                                                                acc[mt][nt], 0, 0, 0);
    }
    #pragma unroll
    for (int nt = 0; nt < 4; ++nt) {
      int col = n0 + nt * 16 + l16;
      float bv = col < 512 ? bias0[col] : bias1[col - 512];
      #pragma unroll
      for (int mt = 0; mt < 4; ++mt) {
        int rb = mbase + mt * 16 + quad * 4;
        #pragma unroll
        for (int r = 0; r < 4; ++r)
          MQ[(size_t)(rb + r) * 1024 + col] = (bf16)(acc[mt][nt][r] + bv);
      }
    }
  } else {
    bool f32 = probe_f32(mask);
    bf16*  qr   = (bf16*)smem;                  // 65536 B
    float* an   = (float*)(smem + 65536);       // 8192 B
    float* sInc = (float*)(smem + 73728);       // 4096 B
    float* rs   = (float*)(smem + 77824);       // 64 B
    float* pd   = (float*)(smem + 77888);       // 64 B
    int bb = blockIdx.x;
    int b = bb >> 4, nc = bb & 15;
    {
      const uint4* src = (const uint4*)((const bf16*)A + ((size_t)b * 1024 + nc * 64) * 512);
      uint4* dst = (uint4*)qr;
      #pragma unroll
      for (int i = 0; i < 16; ++i) dst[t + i * 256] = src[t + i * 256];
    }
    for (int i = t; i < 2048; i += 256) {
      int k = i >> 7, l = i & 127;
      float a0 = ldin(anchors, k * 512 + l, f32);
      float a1 = ldin(anchors, k * 512 + 128 + l, f32);
      float a2 = ldin(anchors, k * 512 + 256 + l, f32);
      float a3 = ldin(anchors, k * 512 + 384 + l, f32);
      an[i] = a0 * a0 + a1 * a1 + a2 * a2 + a3 * a3;
    }
    if (t < 16) {
      float ls = ldin(lsig, t, f32);
      float ssq = __expf(ls); ssq = fmaxf(ssq * ssq, 1e-6f);
      rs[t] = -1.0f / ssq;
      pd[t] = 0.0f;
    }
    __syncthreads();
    {
      int rl = t >> 2, part = t & 3;
      int n = nc * 64 + rl;
      const float* qrow = qn + ((size_t)b * 1024 + n) * 128 + part * 32;
      f32x4 q4[8];
      #pragma unroll
      for (int i = 0; i < 8; ++i) q4[i] = *(const f32x4*)(qrow + i * 4);
      float sc[16] = {};
      #pragma unroll
      for (int i = 0; i < 8; ++i) {
        #pragma unroll
        for (int k = 0; k < 16; ++k) {
          f32x4 av = *(const f32x4*)(an + k * 128 + part * 32 + i * 4);
          sc[k] += q4[i][0] * av[0] + q4[i][1] * av[1] + q4[i][2] * av[2] + q4[i][3] * av[3];
        }
      }
      #pragma unroll
      for (int k = 0; k < 16; ++k) {
        sc[k] += __shfl_xor(sc[k], 1, 64);
        sc[k] += __shfl_xor(sc[k], 2, 64);
      }
      if (part == 0) {
        float mval = ldin(mask, b * 1024 + n, f32);
        #pragma unroll
        for (int k = 0; k < 16; ++k) {
          float inc = __expf(sc[k] * rs[k]) * mval;
          sInc[k * 64 + rl] = inc;
          atomicAdd(&pd[k], inc);
        }
      }
    }
    __syncthreads();
    {
      float acc0[16] = {}, acc1[16] = {};
      for (int nn = 0; nn < 64; ++nn) {
        float v0 = (float)qr[nn * 512 + t];
        float v1 = (float)qr[nn * 512 + 256 + t];
        #pragma unroll
        for (int k = 0; k < 16; ++k) {
          float p = sInc[k * 64 + nn];
          acc0[k] += p * v0;
          acc1[k] += p * v1;
        }
      }
      #pragma unroll
      for (int k = 0; k < 16; ++k) {
        size_t base = ((size_t)(b * 16 + k) * 16 + nc) * 512;
        h_part[base + t] = acc0[k];
        h_part[base + 256 + t] = acc1[k];
      }
    }
    if (t < 16) pd_part[((size_t)(b * 16 + t)) * 16 + nc] = pd[t];
  }
}

// ---------- row-dot against fragment-major packed W ----------
__device__ __forceinline__ float dotW(const char* WallB, int gRow, const float* xp512) {
  const char* p = WallB + (size_t)(gRow >> 6) * 65536
                + (size_t)(((gRow >> 4) & 3) * 1024 + (gRow & 15) * 16);
  float acc = 0.0f;
  #pragma unroll 4
  for (int c4 = 0; c4 < 16; ++c4) {
    #pragma unroll
    for (int cl = 0; cl < 4; ++cl) {
      uint4 u = *(const uint4*)(p + c4 * 4096 + cl * 256);
      const float* xp = xp512 + c4 * 32 + cl * 8;
      acc += xp[0] * bflo(u.x) + xp[1] * bfhi(u.x)
           + xp[2] * bflo(u.y) + xp[3] * bfhi(u.y)
           + xp[4] * bflo(u.z) + xp[5] * bfhi(u.z)
           + xp[6] * bflo(u.w) + xp[7] * bfhi(u.w);
    }
  }
  return acc;
}

// ---------- 3. fused reduce + aggr + K/V: grid (128,2) x 256 ----------
__global__ __launch_bounds__(256) void qlin_akv(
    const float* __restrict__ h_part, const float* __restrict__ pd_part,
    const bf16* __restrict__ Wall, const float* __restrict__ biasF,
    float* __restrict__ Kh, float* __restrict__ Vh) {
  __shared__ float xs[512];
  __shared__ float ys[512];
  const char* WallB = (const char*)Wall;
  const float* ba = biasF + 1536;
  const float* bk = biasF + 2048;
  const float* bv = biasF + 2560;
  int row = blockIdx.x, half = blockIdx.y;
  int t = threadIdx.x;            // 256
  float dsum = 0.0f;
  #pragma unroll
  for (int nc = 0; nc < 16; ++nc) dsum += pd_part[row * 16 + nc];
  float dinv = 1.0f / fmaxf(dsum, 1e-6f);
  #pragma unroll
  for (int j = 0; j < 2; ++j) {
    int d = j * 256 + t;
    float hv = 0.0f;
    #pragma unroll
    for (int nc = 0; nc < 16; ++nc) hv += h_part[(size_t)row * 8192 + nc * 512 + d];
    xs[d] = hv * dinv;
  }
  __syncthreads();
  #pragma unroll
  for (int j = 0; j < 2; ++j) {
    int o = j * 256 + t;
    ys[o] = ba[o] + dotW(WallB, 1536 + o, xs);   // w_aggr = packed matrix 3
  }
  __syncthreads();
  {
    int o = half * 256 + t;
    float ak = bk[o] + dotW(WallB, 2048 + o, ys); // w_k = matrix 4
    float av = bv[o] + dotW(WallB, 2560 + o, ys); // w_v = matrix 5
    Kh[(size_t)row * 512 + o] = ak;
    Vh[(size_t)row * 512 + o] = av;
  }
}

// ---------- 4. fused attention + gemm2(Wo) + residual + quaternion LN ----------
// 512 blocks x 256 threads; block = 16 rows end-to-end.
__global__ __launch_bounds__(256, 2) void attn_tail(
    const bf16* __restrict__ MQ, const float* __restrict__ Kh_g,
    const float* __restrict__ Vh_g, const bf16* __restrict__ Wall,
    const float* __restrict__ biasF, const void* q, const void* mask, void* out) {
  __shared__ float KV[8 * 1092];      // 34944 B; later aliased as 16KB A_lds
  __shared__ float P[16 * 132];       // 8448 B
  const bool f32 = probe_f32(mask);
  const int t = threadIdx.x;
  const int rowbase = blockIdx.x * 16;
  const int b = rowbase >> 10;
  // --- K scores + softmax (identical to verified attn_v3) ---
  for (int i = t; i < 8192; i += 256) {
    int k = i >> 9, d = i & 511, h = d >> 6, dd = d & 63;
    KV[h * 1092 + k * 68 + dd] = Kh_g[(size_t)b * 8192 + i];
  }
  __syncthreads();
  {
    const int r = t >> 4, h = (t >> 1) & 7, hf = t & 1;
    const int grow = rowbase + r;
    const uint4* qp = (const uint4*)(MQ + (size_t)grow * 1024 + 512 + h * 64 + hf * 32);
    float qv[32];
    #pragma unroll
    for (int i = 0; i < 4; ++i) {
      uint4 u = qp[i];
      qv[i * 8 + 0] = bflo(u.x); qv[i * 8 + 1] = bfhi(u.x);
      qv[i * 8 + 2] = bflo(u.y); qv[i * 8 + 3] = bfhi(u.y);
      qv[i * 8 + 4] = bflo(u.z); qv[i * 8 + 5] = bfhi(u.z);
      qv[i * 8 + 6] = bflo(u.w); qv[i * 8 + 7] = bfhi(u.w);
    }
    float sc[16];
    #pragma unroll
    for (int k = 0; k < 16; ++k) {
      float s = 0.0f;
      #pragma unroll
      for (int d4 = 0; d4 < 8; ++d4) {
        f32x4 kv = *(const f32x4*)(KV + h * 1092 + k * 68 + hf * 32 + d4 * 4);
        s += qv[d4 * 4 + 0] * kv[0] + qv[d4 * 4 + 1] * kv[1]
           + qv[d4 * 4 + 2] * kv[2] + qv[d4 * 4 + 3] * kv[3];
      }
      sc[k] = s;
    }
    #pragma unroll
    for (int k = 0; k < 16; ++k) sc[k] += __shfl_xor(sc[k], 1, 64);
    if (hf == 0) {
      #pragma unroll
      for (int k = 0; k < 16; ++k) sc[k] *= 0.125f;
      float m = sc[0];
      #pragma unroll
      for (int k = 1; k < 16; ++k) m = fmaxf(m, sc[k]);
      float ssum = 0.0f;
      #pragma unroll
      for (int k = 0; k < 16; ++k) { sc[k] = __expf(sc[k] - m); ssum += sc[k]; }
      float inv = 1.0f / ssum;
      #pragma unroll
      for (int k = 0; k < 16; ++k) P[r * 132 + h * 16 + k] = sc[k] * inv;
    }
  }
  __syncthreads();
  for (int i = t; i < 8192; i += 256) {
    int k = i >> 9, d = i & 511, h = d >> 6, dd = d & 63;
    KV[h * 1092 + k * 68 + dd] = Vh_g[(size_t)b * 8192 + i];
  }
  __syncthreads();
  // --- PV into registers ---
  float pv[8][4];
  {
    const int r = t >> 4, dg = t & 15;
    #pragma unroll
    for (int h = 0; h < 8; ++h) {
      float a0 = 0, a1 = 0, a2 = 0, a3 = 0;
      #pragma unroll
      for (int k = 0; k < 16; ++k) {
        float p = P[r * 132 + h * 16 + k];
        f32x4 va = *(const f32x4*)(KV + h * 1092 + k * 68 + dg * 4);
        a0 += p * va[0]; a1 += p * va[1]; a2 += p * va[2]; a3 += p * va[3];
      }
      pv[h][0] = a0; pv[h][1] = a1; pv[h][2] = a2; pv[h][3] = a3;
    }
  }
  __syncthreads();                       // all PV reads of KV done
  // --- write fragment-major A-tile (aliases KV region, 16KB) ---
  char* A_lds = (char*)KV;
  {
    const int r = t >> 4, dg = t & 15;
    #pragma unroll
    for (int h = 0; h < 8; ++h) {
      int c0 = h * 64 + dg * 4;
      int off = (c0 >> 5) * 1024 + ((c0 >> 3) & 3) * 256 + r * 16 + (c0 & 7) * 2;
      bf16 ov[4] = {(bf16)pv[h][0], (bf16)pv[h][1], (bf16)pv[h][2], (bf16)pv[h][3]};
      *(uint2*)(A_lds + off) = *(const uint2*)ov;
    }
  }
  __syncthreads();
  // --- gemm2: 16 rows x 512 cols, Wo fragments straight from L2 ---
  const int wave = t >> 6, lane = t & 63, quad = lane >> 4, l16 = lane & 15;
  const char* WallB = (const char*)Wall;
  f32x4 acc[8] = {};
  bf16x8 breg[2][8];
  bf16x8 areg[2];
  areg[0] = *(const bf16x8*)(A_lds + quad * 256 + l16 * 16);
  #pragma unroll
  for (int nt = 0; nt < 8; ++nt) {
    size_t cb = (size_t)(16 + wave * 2 + (nt >> 2)) * 65536;
    breg[0][nt] = *(const bf16x8*)(WallB + cb + (nt & 3) * 1024 + lane * 16);
  }
  #pragma unroll
  for (int kk = 0; kk < 16; ++kk) {
    const int cur = kk & 1, nxt = cur ^ 1;
    if (kk < 15) {
      areg[nxt] = *(const bf16x8*)(A_lds + (kk + 1) * 1024 + quad * 256 + l16 * 16);
      #pragma unroll
      for (int nt = 0; nt < 8; ++nt) {
        size_t cb = (size_t)(16 + wave * 2 + (nt >> 2)) * 65536;
        breg[nxt][nt] = *(const bf16x8*)(WallB + cb + (kk + 1) * 4096 + (nt & 3) * 1024 + lane * 16);
      }
    }
    #pragma unroll
    for (int nt = 0; nt < 8; ++nt)
      acc[nt] = __builtin_amdgcn_mfma_f32_16x16x32_bf16(areg[cur], breg[cur][nt], acc[nt], 0, 0, 0);
  }
  // --- epilogue: +bias_o, +q, +msg_p(MQ), per-component LN, write out ---
  const float* biasO = biasF + 1024;
  const float* gamF = biasF + 3072;
  float xv[8][4];
  float s[4] = {0, 0, 0, 0}, s2[4] = {0, 0, 0, 0};
  #pragma unroll
  for (int nt = 0; nt < 8; ++nt) {
    int gcol = wave * 128 + nt * 16 + l16;
    float bo = biasO[gcol];
    #pragma unroll
    for (int reg = 0; reg < 4; ++reg) {
      int grow = rowbase + quad * 4 + reg;
      float qv = ldin(q, (size_t)grow * 512 + gcol, f32);
      float mp = (float)MQ[(size_t)grow * 1024 + gcol];
      float x = qv + mp + acc[nt][reg] + bo;
      xv[nt][reg] = x;
      s[reg] += x; s2[reg] += x * x;
    }
  }
  #pragma unroll
  for (int reg = 0; reg < 4; ++reg) {
    #pragma unroll
    for (int off = 1; off <= 8; off <<= 1) {
      s[reg]  += __shfl_xor(s[reg], off, 64);
      s2[reg] += __shfl_xor(s2[reg], off, 64);
    }
  }
  #pragma unroll
  for (int reg = 0; reg < 4; ++reg) {
    float m = s[reg] * (1.0f / 128.0f);
    float rinv = rsqrtf(s2[reg] * (1.0f / 128.0f) - m * m + 1e-5f);
    int grow = rowbase + quad * 4 + reg;
    #pragma unroll
    for (int nt = 0; nt < 8; ++nt) {
      int gcol = wave * 128 + nt * 16 + l16;
      float y = (xv[nt][reg] - m) * rinv * gamF[gcol] + gamF[512 + gcol];
      if (f32) ((float*)out)[(size_t)grow * 512 + gcol] = y;
      else     ((bf16*)out)[(size_t)grow * 512 + gcol] = (bf16)y;
    }
  }
}

// ---------- launch ----------
extern "C" void kernel_launch(void* const* d_in, const int* in_sizes, int n_in,
                              void* d_out, int out_size, void* d_ws, size_t ws_size,
                              hipStream_t stream) {
  (void)in_sizes; (void)n_in; (void)out_size; (void)ws_size;
  const void* q      = d_in[0];
  const void* spike  = d_in[1];
  const void* mask   = d_in[2];
  const void* tl     = d_in[3];
  const void* w_prim = d_in[4];
  const void* b_prim = d_in[5];
  const void* anchors= d_in[6];
  const void* lsig   = d_in[7];
  const void* w_aggr = d_in[8];
  const void* b_aggr = d_in[9];
  const void* w_q    = d_in[10];
  const void* b_q    = d_in[11];
  const void* w_k    = d_in[12];
  const void* b_k    = d_in[13];
  const void* w_v    = d_in[14];
  const void* b_v    = d_in[15];
  const void* w_o    = d_in[16];
  const void* b_o    = d_in[17];
  const void* gam    = d_in[18];
  const void* bet    = d_in[19];

  char* ws = (char*)d_ws;
  bf16*  Wall   = (bf16*)(ws + 0);            // 3,145,728 (fragment-major packed)
  bf16*  q_rot  = (bf16*)(ws + 3145728);      // 8,388,608
  float* qn     = (float*)(ws + 11534336);    // 4,194,304
  bf16*  MQ     = (bf16*)(ws + 15728640);     // 16,777,216
  float* h_part = (float*)(ws + 32505856);    // 4,194,304
  float* pd_part= (float*)(ws + 36700160);    // 8,192
  float* Kh     = (float*)(ws + 36708352);    // 262,144
  float* Vh     = (float*)(ws + 36970496);    // 262,144
  float* biasF  = (float*)(ws + 37232640);    // 16,384

  prologue<<<5640, 256, 0, stream>>>(w_prim, w_q, w_o, w_aggr, w_k, w_v,
                                     b_prim, b_q, b_o, b_aggr, b_k, b_v, gam, bet,
                                     q, spike, tl, mask, Wall, biasF, q_rot, qn);
  gemm_dist<<<640, 256, 0, stream>>>(q_rot, Wall, biasF + 0, biasF + 512, MQ,
                                     qn, anchors, lsig, mask, h_part, pd_part);
  qlin_akv<<<dim3(128, 2), 256, 0, stream>>>(h_part, pd_part, Wall, biasF, Kh, Vh);
  attn_tail<<<512, 256, 0, stream>>>(MQ, Kh, Vh, Wall, biasF, q, mask, d_out);
}

// Round 4
// 195.462 us; speedup vs baseline: 2.1837x; 1.1654x over previous
//
#include <hip/hip_runtime.h>
#include <hip/hip_bf16.h>

typedef __hip_bfloat16 bf16;
typedef __attribute__((ext_vector_type(8))) short bf16x8;
typedef __attribute__((ext_vector_type(4))) float f32x4;

// ---------- helpers ----------
__device__ __forceinline__ float bflo(unsigned u) { return __uint_as_float(u << 16); }
__device__ __forceinline__ float bfhi(unsigned u) { return __uint_as_float(u & 0xffff0000u); }
__device__ __forceinline__ bool probe_f32(const void* mask) {
  return *(const unsigned*)mask == 0x3F800000u;
}
__device__ __forceinline__ float ldin(const void* p, size_t i, bool f32) {
  return f32 ? ((const float*)p)[i] : (float)((const bf16*)p)[i];
}

// Fragment-major pack layout (global): for global row g (0..3071), col k (0..511):
//   chunk = g>>6 (64-row chunk, 65536 B each), r = g&63, c = k>>3 (16B block)
//   byte off = chunk*65536 + (c>>2)*4096 + (r>>4)*1024 + ((c&3)*16 + (r&15))*16 + (k&7)*2

// ---------- 1. prologue: pack_w (fragment-major) + biases + spike rotation ----------
__global__ __launch_bounds__(256) void prologue(
    const void* w0, const void* w1, const void* w2, const void* w3,
    const void* w4, const void* w5,
    const void* b0, const void* b1, const void* b2, const void* b3,
    const void* b4, const void* b5, const void* g_, const void* be,
    const void* q, const void* spike, const void* theta_logit, const void* mask,
    bf16* __restrict__ Wall, float* __restrict__ biasF,
    bf16* __restrict__ q_rot, float* __restrict__ qn) {
  bool f32 = probe_f32(mask);
  int blk = blockIdx.x, t = threadIdx.x;
  if (blk < 1536) {
    const int compT[4][4] = {{0,1,2,3},{1,0,3,2},{2,3,0,1},{3,2,1,0}};
    const float signT[4][4] = {{1.f,-1.f,-1.f,-1.f},{1.f,1.f,-1.f,1.f},{1.f,1.f,1.f,-1.f},{1.f,-1.f,1.f,1.f}};
    int E = blk * 1024 + t * 4;
    int g = E >> 9;            // global packed row 0..3071
    int wi = g >> 9;           // matrix index 0..5
    int o = g & 511;           // row within matrix
    int k0 = E & 511;          // col (multiple of 4)
    const void* src = wi == 0 ? w0 : wi == 1 ? w1 : wi == 2 ? w2 : wi == 3 ? w3 : wi == 4 ? w4 : w5;
    int ro = o >> 7, a = o & 127, co = k0 >> 7;
    int comp = compT[ro][co];
    float sgn = signT[ro][co];
    bf16 ov[4];
    #pragma unroll
    for (int j = 0; j < 4; ++j) {
      int b2 = (k0 & 127) + j;
      ov[j] = (bf16)(ldin(src, comp * 16384 + a * 128 + b2, f32) * sgn);
    }
    int r = g & 63, c = k0 >> 3;
    size_t off = (size_t)(g >> 6) * 65536 + (size_t)((c >> 2) * 4096 + (r >> 4) * 1024
               + ((c & 3) * 16 + (r & 15)) * 16 + (k0 & 7) * 2);
    *(uint2*)((char*)Wall + off) = *(const uint2*)ov;
  } else if (blk < 1544) {
    int b = blk - 1536;
    const void* src = b == 0 ? b0 : b == 1 ? b1 : b == 2 ? b2 : b == 3 ? b3
                    : b == 4 ? b4 : b == 5 ? b5 : b == 6 ? g_ : be;
    biasF[b * 512 + t] = ldin(src, t, f32);
    biasF[b * 512 + 256 + t] = ldin(src, 256 + t, f32);
  } else {
    int row = (blk - 1544) * 2 + (t >> 7);
    int l = t & 127;
    float tl = ldin(theta_logit, 0, f32);
    float tmax = 1.5707963267948966f / (1.0f + __expf(-tl));
    float th = tmax * ldin(spike, row, f32);
    float c = cosf(th), s = sinf(th);
    size_t base = (size_t)row * 512;
    float a = ldin(q, base + l, f32), b = ldin(q, base + 128 + l, f32);
    float cc = ldin(q, base + 256 + l, f32), d = ldin(q, base + 384 + l, f32);
    float r0 = c * a - s * d;
    float r1 = c * b - s * cc;
    float r2 = c * cc + s * b;
    float r3 = c * d + s * a;
    bf16* orow = q_rot + base;
    orow[l] = (bf16)r0; orow[128 + l] = (bf16)r1; orow[256 + l] = (bf16)r2; orow[384 + l] = (bf16)r3;
    qn[(size_t)row * 128 + l] = r0 * r0 + r1 * r1 + r2 * r2 + r3 * r3;
  }
}

// ---------- staging: straight coalesced 64KB copy (Wall already fragment-major) ----------
__device__ __forceinline__ void stage_B64(const bf16* __restrict__ Bw, int n0, char* Bs, int t) {
  const char* src = (const char*)Bw + (size_t)(n0 >> 6) * 65536;
  #pragma unroll
  for (int i = 0; i < 16; ++i)
    *(uint4*)(Bs + t * 16 + i * 4096) = *(const uint4*)(src + t * 16 + i * 4096);
}

// ---------- 2. FUSED dist_h + gemm1 ----------
__global__ __launch_bounds__(256, 2) void gemm_dist(
    const bf16* __restrict__ A, const bf16* __restrict__ Bw,
    const float* __restrict__ bias0, const float* __restrict__ bias1,
    bf16* __restrict__ MQ,
    const float* __restrict__ qn, const void* anchors, const void* lsig,
    const void* mask, float* __restrict__ h_part, float* __restrict__ pd_part) {
  __shared__ char smem[77952];
  const int t = threadIdx.x;
  if (blockIdx.x >= 128) {
    char* Bs = smem;
    const int g = blockIdx.x - 128;
    const int wave = t >> 6, lane = t & 63;
    const int quad = lane >> 4, l16 = lane & 15;
    const int m0 = (g & 31) * 256, n0 = (g >> 5) * 64;
    stage_B64(Bw, n0, Bs, t);
    __syncthreads();
    const int mbase = m0 + wave * 64;
    f32x4 acc[4][4] = {};
    bf16x8 areg[2][4], breg[2][4];
    #pragma unroll
    for (int mt = 0; mt < 4; ++mt)
      areg[0][mt] = *(const bf16x8*)(A + (size_t)(mbase + mt * 16 + l16) * 512 + quad * 8);
    #pragma unroll
    for (int nt = 0; nt < 4; ++nt)
      breg[0][nt] = *(const bf16x8*)(Bs + nt * 1024 + lane * 16);
    #pragma unroll
    for (int kk = 0; kk < 16; ++kk) {
      const int cur = kk & 1, nxt = cur ^ 1;
      if (kk < 15) {
        const int k2 = (kk + 1) * 32;
        #pragma unroll
        for (int mt = 0; mt < 4; ++mt)
          areg[nxt][mt] = *(const bf16x8*)(A + (size_t)(mbase + mt * 16 + l16) * 512 + k2 + quad * 8);
        #pragma unroll
        for (int nt = 0; nt < 4; ++nt)
          breg[nxt][nt] = *(const bf16x8*)(Bs + (kk + 1) * 4096 + nt * 1024 + lane * 16);
      }
      #pragma unroll
      for (int mt = 0; mt < 4; ++mt)
        #pragma unroll
        for (int nt = 0; nt < 4; ++nt)
          acc[mt][nt] = __builtin_amdgcn_mfma_f32_16x16x32_bf16(areg[cur][mt], breg[cur][nt],
                                                                acc[mt][nt], 0, 0, 0);
    }
    #pragma unroll
    for (int nt = 0; nt < 4; ++nt) {
      int col = n0 + nt * 16 + l16;
      float bv = col < 512 ? bias0[col] : bias1[col - 512];
      #pragma unroll
      for (int mt = 0; mt < 4; ++mt) {
        int rb = mbase + mt * 16 + quad * 4;
        #pragma unroll
        for (int r = 0; r < 4; ++r)
          MQ[(size_t)(rb + r) * 1024 + col] = (bf16)(acc[mt][nt][r] + bv);
      }
    }
  } else {
    bool f32 = probe_f32(mask);
    bf16*  qr   = (bf16*)smem;                  // 65536 B
    float* an   = (float*)(smem + 65536);       // 8192 B
    float* sInc = (float*)(smem + 73728);       // 4096 B
    float* rs   = (float*)(smem + 77824);       // 64 B
    float* pd   = (float*)(smem + 77888);       // 64 B
    int bb = blockIdx.x;
    int b = bb >> 4, nc = bb & 15;
    {
      const uint4* src = (const uint4*)((const bf16*)A + ((size_t)b * 1024 + nc * 64) * 512);
      uint4* dst = (uint4*)qr;
      #pragma unroll
      for (int i = 0; i < 16; ++i) dst[t + i * 256] = src[t + i * 256];
    }
    for (int i = t; i < 2048; i += 256) {
      int k = i >> 7, l = i & 127;
      float a0 = ldin(anchors, k * 512 + l, f32);
      float a1 = ldin(anchors, k * 512 + 128 + l, f32);
      float a2 = ldin(anchors, k * 512 + 256 + l, f32);
      float a3 = ldin(anchors, k * 512 + 384 + l, f32);
      an[i] = a0 * a0 + a1 * a1 + a2 * a2 + a3 * a3;
    }
    if (t < 16) {
      float ls = ldin(lsig, t, f32);
      float ssq = __expf(ls); ssq = fmaxf(ssq * ssq, 1e-6f);
      rs[t] = -1.0f / ssq;
      pd[t] = 0.0f;
    }
    __syncthreads();
    {
      int rl = t >> 2, part = t & 3;
      int n = nc * 64 + rl;
      const float* qrow = qn + ((size_t)b * 1024 + n) * 128 + part * 32;
      f32x4 q4[8];
      #pragma unroll
      for (int i = 0; i < 8; ++i) q4[i] = *(const f32x4*)(qrow + i * 4);
      float sc[16] = {};
      #pragma unroll
      for (int i = 0; i < 8; ++i) {
        #pragma unroll
        for (int k = 0; k < 16; ++k) {
          f32x4 av = *(const f32x4*)(an + k * 128 + part * 32 + i * 4);
          sc[k] += q4[i][0] * av[0] + q4[i][1] * av[1] + q4[i][2] * av[2] + q4[i][3] * av[3];
        }
      }
      #pragma unroll
      for (int k = 0; k < 16; ++k) {
        sc[k] += __shfl_xor(sc[k], 1, 64);
        sc[k] += __shfl_xor(sc[k], 2, 64);
      }
      if (part == 0) {
        float mval = ldin(mask, b * 1024 + n, f32);
        #pragma unroll
        for (int k = 0; k < 16; ++k) {
          float inc = __expf(sc[k] * rs[k]) * mval;
          sInc[k * 64 + rl] = inc;
          atomicAdd(&pd[k], inc);
        }
      }
    }
    __syncthreads();
    {
      float acc0[16] = {}, acc1[16] = {};
      for (int nn = 0; nn < 64; ++nn) {
        float v0 = (float)qr[nn * 512 + t];
        float v1 = (float)qr[nn * 512 + 256 + t];
        #pragma unroll
        for (int k = 0; k < 16; ++k) {
          float p = sInc[k * 64 + nn];
          acc0[k] += p * v0;
          acc1[k] += p * v1;
        }
      }
      #pragma unroll
      for (int k = 0; k < 16; ++k) {
        size_t base = ((size_t)(b * 16 + k) * 16 + nc) * 512;
        h_part[base + t] = acc0[k];
        h_part[base + 256 + t] = acc1[k];
      }
    }
    if (t < 16) pd_part[((size_t)(b * 16 + t)) * 16 + nc] = pd[t];
  }
}

// ---------- partial row-dot against fragment-major packed W (4 of 16 col-chunks) ----------
__device__ __forceinline__ float dotW4(const char* WallB, int gRow, const float* xp512, int c4lo) {
  const char* p = WallB + (size_t)(gRow >> 6) * 65536
                + (size_t)(((gRow >> 4) & 3) * 1024 + (gRow & 15) * 16);
  float acc = 0.0f;
  #pragma unroll
  for (int c4 = c4lo; c4 < c4lo + 4; ++c4) {
    #pragma unroll
    for (int cl = 0; cl < 4; ++cl) {
      uint4 u = *(const uint4*)(p + c4 * 4096 + cl * 256);
      const float* xp = xp512 + c4 * 32 + cl * 8;
      acc += xp[0] * bflo(u.x) + xp[1] * bfhi(u.x)
           + xp[2] * bflo(u.y) + xp[3] * bfhi(u.y)
           + xp[4] * bflo(u.z) + xp[5] * bfhi(u.z)
           + xp[6] * bflo(u.w) + xp[7] * bfhi(u.w);
    }
  }
  return acc;
}

// ---------- 3a. reduce + aggr projection: grid 1024 (gy=bx>>7, row=bx&127) ----------
// Each block: full row reduce (redundant, L3-resident) + 64 aggr outputs,
// 4 lanes per output (128 MACs each) -> shuffle combine. 4 blocks/CU.
__global__ __launch_bounds__(256) void aggr_k(
    const float* __restrict__ h_part, const float* __restrict__ pd_part,
    const bf16* __restrict__ Wall, const float* __restrict__ biasF,
    float* __restrict__ h_aggr) {
  __shared__ float xs[512];
  const char* WallB = (const char*)Wall;
  const float* ba = biasF + 1536;
  const int gy = blockIdx.x >> 7, row = blockIdx.x & 127;
  const int t = threadIdx.x;
  float dsum = 0.0f;
  #pragma unroll
  for (int nc = 0; nc < 16; ++nc) dsum += pd_part[row * 16 + nc];
  float dinv = 1.0f / fmaxf(dsum, 1e-6f);
  #pragma unroll
  for (int j = 0; j < 2; ++j) {
    int d = j * 256 + t;
    float hv = 0.0f;
    #pragma unroll
    for (int nc = 0; nc < 16; ++nc) hv += h_part[(size_t)row * 8192 + nc * 512 + d];
    xs[d] = hv * dinv;
  }
  __syncthreads();
  const int o = gy * 64 + (t >> 2), part = t & 3;
  float acc = dotW4(WallB, 1536 + o, xs, part * 4);
  acc += __shfl_xor(acc, 1, 64);
  acc += __shfl_xor(acc, 2, 64);
  if (part == 0) h_aggr[(size_t)row * 512 + o] = acc + ba[o];
}

// ---------- 3b. K/V projections: grid 1024 (gy=bx>>7, row=bx&127) ----------
__global__ __launch_bounds__(256) void kv_k(
    const float* __restrict__ h_aggr, const bf16* __restrict__ Wall,
    const float* __restrict__ biasF,
    float* __restrict__ Kh, float* __restrict__ Vh) {
  __shared__ float ys[512];
  const char* WallB = (const char*)Wall;
  const float* bk = biasF + 2048;
  const float* bv = biasF + 2560;
  const int gy = blockIdx.x >> 7, row = blockIdx.x & 127;
  const int t = threadIdx.x;
  #pragma unroll
  for (int j = 0; j < 2; ++j) {
    int d = j * 256 + t;
    ys[d] = h_aggr[(size_t)row * 512 + d];
  }
  __syncthreads();
  const int o = gy * 64 + (t >> 2), part = t & 3;
  float ak = dotW4(WallB, 2048 + o, ys, part * 4);
  float av = dotW4(WallB, 2560 + o, ys, part * 4);
  ak += __shfl_xor(ak, 1, 64);
  ak += __shfl_xor(ak, 2, 64);
  av += __shfl_xor(av, 1, 64);
  av += __shfl_xor(av, 2, 64);
  if (part == 0) {
    Kh[(size_t)row * 512 + o] = ak + bk[o];
    Vh[(size_t)row * 512 + o] = av + bv[o];
  }
}

// ---------- 4. fused attention + gemm2(Wo) + residual + quaternion LN ----------
__global__ __launch_bounds__(256, 2) void attn_tail(
    const bf16* __restrict__ MQ, const float* __restrict__ Kh_g,
    const float* __restrict__ Vh_g, const bf16* __restrict__ Wall,
    const float* __restrict__ biasF, const void* q, const void* mask, void* out) {
  __shared__ float KV[8 * 1092];      // 34944 B; later aliased as 16KB A_lds
  __shared__ float P[16 * 132];       // 8448 B
  const bool f32 = probe_f32(mask);
  const int t = threadIdx.x;
  const int rowbase = blockIdx.x * 16;
  const int b = rowbase >> 10;
  for (int i = t; i < 8192; i += 256) {
    int k = i >> 9, d = i & 511, h = d >> 6, dd = d & 63;
    KV[h * 1092 + k * 68 + dd] = Kh_g[(size_t)b * 8192 + i];
  }
  __syncthreads();
  {
    const int r = t >> 4, h = (t >> 1) & 7, hf = t & 1;
    const int grow = rowbase + r;
    const uint4* qp = (const uint4*)(MQ + (size_t)grow * 1024 + 512 + h * 64 + hf * 32);
    float qv[32];
    #pragma unroll
    for (int i = 0; i < 4; ++i) {
      uint4 u = qp[i];
      qv[i * 8 + 0] = bflo(u.x); qv[i * 8 + 1] = bfhi(u.x);
      qv[i * 8 + 2] = bflo(u.y); qv[i * 8 + 3] = bfhi(u.y);
      qv[i * 8 + 4] = bflo(u.z); qv[i * 8 + 5] = bfhi(u.z);
      qv[i * 8 + 6] = bflo(u.w); qv[i * 8 + 7] = bfhi(u.w);
    }
    float sc[16];
    #pragma unroll
    for (int k = 0; k < 16; ++k) {
      float s = 0.0f;
      #pragma unroll
      for (int d4 = 0; d4 < 8; ++d4) {
        f32x4 kv = *(const f32x4*)(KV + h * 1092 + k * 68 + hf * 32 + d4 * 4);
        s += qv[d4 * 4 + 0] * kv[0] + qv[d4 * 4 + 1] * kv[1]
           + qv[d4 * 4 + 2] * kv[2] + qv[d4 * 4 + 3] * kv[3];
      }
      sc[k] = s;
    }
    #pragma unroll
    for (int k = 0; k < 16; ++k) sc[k] += __shfl_xor(sc[k], 1, 64);
    if (hf == 0) {
      #pragma unroll
      for (int k = 0; k < 16; ++k) sc[k] *= 0.125f;
      float m = sc[0];
      #pragma unroll
      for (int k = 1; k < 16; ++k) m = fmaxf(m, sc[k]);
      float ssum = 0.0f;
      #pragma unroll
      for (int k = 0; k < 16; ++k) { sc[k] = __expf(sc[k] - m); ssum += sc[k]; }
      float inv = 1.0f / ssum;
      #pragma unroll
      for (int k = 0; k < 16; ++k) P[r * 132 + h * 16 + k] = sc[k] * inv;
    }
  }
  __syncthreads();
  for (int i = t; i < 8192; i += 256) {
    int k = i >> 9, d = i & 511, h = d >> 6, dd = d & 63;
    KV[h * 1092 + k * 68 + dd] = Vh_g[(size_t)b * 8192 + i];
  }
  __syncthreads();
  float pv[8][4];
  {
    const int r = t >> 4, dg = t & 15;
    #pragma unroll
    for (int h = 0; h < 8; ++h) {
      float a0 = 0, a1 = 0, a2 = 0, a3 = 0;
      #pragma unroll
      for (int k = 0; k < 16; ++k) {
        float p = P[r * 132 + h * 16 + k];
        f32x4 va = *(const f32x4*)(KV + h * 1092 + k * 68 + dg * 4);
        a0 += p * va[0]; a1 += p * va[1]; a2 += p * va[2]; a3 += p * va[3];
      }
      pv[h][0] = a0; pv[h][1] = a1; pv[h][2] = a2; pv[h][3] = a3;
    }
  }
  __syncthreads();
  char* A_lds = (char*)KV;
  {
    const int r = t >> 4, dg = t & 15;
    #pragma unroll
    for (int h = 0; h < 8; ++h) {
      int c0 = h * 64 + dg * 4;
      int off = (c0 >> 5) * 1024 + ((c0 >> 3) & 3) * 256 + r * 16 + (c0 & 7) * 2;
      bf16 ov[4] = {(bf16)pv[h][0], (bf16)pv[h][1], (bf16)pv[h][2], (bf16)pv[h][3]};
      *(uint2*)(A_lds + off) = *(const uint2*)ov;
    }
  }
  __syncthreads();
  const int wave = t >> 6, lane = t & 63, quad = lane >> 4, l16 = lane & 15;
  const char* WallB = (const char*)Wall;
  f32x4 acc[8] = {};
  bf16x8 breg[2][8];
  bf16x8 areg[2];
  areg[0] = *(const bf16x8*)(A_lds + quad * 256 + l16 * 16);
  #pragma unroll
  for (int nt = 0; nt < 8; ++nt) {
    size_t cb = (size_t)(16 + wave * 2 + (nt >> 2)) * 65536;
    breg[0][nt] = *(const bf16x8*)(WallB + cb + (nt & 3) * 1024 + lane * 16);
  }
  #pragma unroll
  for (int kk = 0; kk < 16; ++kk) {
    const int cur = kk & 1, nxt = cur ^ 1;
    if (kk < 15) {
      areg[nxt] = *(const bf16x8*)(A_lds + (kk + 1) * 1024 + quad * 256 + l16 * 16);
      #pragma unroll
      for (int nt = 0; nt < 8; ++nt) {
        size_t cb = (size_t)(16 + wave * 2 + (nt >> 2)) * 65536;
        breg[nxt][nt] = *(const bf16x8*)(WallB + cb + (kk + 1) * 4096 + (nt & 3) * 1024 + lane * 16);
      }
    }
    #pragma unroll
    for (int nt = 0; nt < 8; ++nt)
      acc[nt] = __builtin_amdgcn_mfma_f32_16x16x32_bf16(areg[cur], breg[cur][nt], acc[nt], 0, 0, 0);
  }
  const float* biasO = biasF + 1024;
  const float* gamF = biasF + 3072;
  float xv[8][4];
  float s[4] = {0, 0, 0, 0}, s2[4] = {0, 0, 0, 0};
  #pragma unroll
  for (int nt = 0; nt < 8; ++nt) {
    int gcol = wave * 128 + nt * 16 + l16;
    float bo = biasO[gcol];
    #pragma unroll
    for (int reg = 0; reg < 4; ++reg) {
      int grow = rowbase + quad * 4 + reg;
      float qv = ldin(q, (size_t)grow * 512 + gcol, f32);
      float mp = (float)MQ[(size_t)grow * 1024 + gcol];
      float x = qv + mp + acc[nt][reg] + bo;
      xv[nt][reg] = x;
      s[reg] += x; s2[reg] += x * x;
    }
  }
  #pragma unroll
  for (int reg = 0; reg < 4; ++reg) {
    #pragma unroll
    for (int off = 1; off <= 8; off <<= 1) {
      s[reg]  += __shfl_xor(s[reg], off, 64);
      s2[reg] += __shfl_xor(s2[reg], off, 64);
    }
  }
  #pragma unroll
  for (int reg = 0; reg < 4; ++reg) {
    float m = s[reg] * (1.0f / 128.0f);
    float rinv = rsqrtf(s2[reg] * (1.0f / 128.0f) - m * m + 1e-5f);
    int grow = rowbase + quad * 4 + reg;
    #pragma unroll
    for (int nt = 0; nt < 8; ++nt) {
      int gcol = wave * 128 + nt * 16 + l16;
      float y = (xv[nt][reg] - m) * rinv * gamF[gcol] + gamF[512 + gcol];
      if (f32) ((float*)out)[(size_t)grow * 512 + gcol] = y;
      else     ((bf16*)out)[(size_t)grow * 512 + gcol] = (bf16)y;
    }
  }
}

// ---------- launch ----------
extern "C" void kernel_launch(void* const* d_in, const int* in_sizes, int n_in,
                              void* d_out, int out_size, void* d_ws, size_t ws_size,
                              hipStream_t stream) {
  (void)in_sizes; (void)n_in; (void)out_size; (void)ws_size;
  const void* q      = d_in[0];
  const void* spike  = d_in[1];
  const void* mask   = d_in[2];
  const void* tl     = d_in[3];
  const void* w_prim = d_in[4];
  const void* b_prim = d_in[5];
  const void* anchors= d_in[6];
  const void* lsig   = d_in[7];
  const void* w_aggr = d_in[8];
  const void* b_aggr = d_in[9];
  const void* w_q    = d_in[10];
  const void* b_q    = d_in[11];
  const void* w_k    = d_in[12];
  const void* b_k    = d_in[13];
  const void* w_v    = d_in[14];
  const void* b_v    = d_in[15];
  const void* w_o    = d_in[16];
  const void* b_o    = d_in[17];
  const void* gam    = d_in[18];
  const void* bet    = d_in[19];

  char* ws = (char*)d_ws;
  bf16*  Wall   = (bf16*)(ws + 0);            // 3,145,728 (fragment-major packed)
  bf16*  q_rot  = (bf16*)(ws + 3145728);      // 8,388,608
  float* qn     = (float*)(ws + 11534336);    // 4,194,304
  bf16*  MQ     = (bf16*)(ws + 15728640);     // 16,777,216
  float* h_part = (float*)(ws + 32505856);    // 4,194,304
  float* pd_part= (float*)(ws + 36700160);    // 8,192
  float* Kh     = (float*)(ws + 36708352);    // 262,144
  float* Vh     = (float*)(ws + 36970496);    // 262,144
  float* biasF  = (float*)(ws + 37232640);    // 16,384
  float* h_aggr = (float*)(ws + 37249024);    // 262,144 (end 37,511,168)

  prologue<<<5640, 256, 0, stream>>>(w_prim, w_q, w_o, w_aggr, w_k, w_v,
                                     b_prim, b_q, b_o, b_aggr, b_k, b_v, gam, bet,
                                     q, spike, tl, mask, Wall, biasF, q_rot, qn);
  gemm_dist<<<640, 256, 0, stream>>>(q_rot, Wall, biasF + 0, biasF + 512, MQ,
                                     qn, anchors, lsig, mask, h_part, pd_part);
  aggr_k<<<1024, 256, 0, stream>>>(h_part, pd_part, Wall, biasF, h_aggr);
  kv_k<<<1024, 256, 0, stream>>>(h_aggr, Wall, biasF, Kh, Vh);
  attn_tail<<<512, 256, 0, stream>>>(MQ, Kh, Vh, Wall, biasF, q, mask, d_out);
}

// Round 6
// 189.049 us; speedup vs baseline: 2.2578x; 1.0339x over previous
//
#include <hip/hip_runtime.h>
#include <hip/hip_bf16.h>

typedef __hip_bfloat16 bf16;
typedef __attribute__((ext_vector_type(8))) short bf16x8;
typedef __attribute__((ext_vector_type(4))) float f32x4;

// ---------- helpers ----------
__device__ __forceinline__ float bflo(unsigned u) { return __uint_as_float(u << 16); }
__device__ __forceinline__ float bfhi(unsigned u) { return __uint_as_float(u & 0xffff0000u); }
__device__ __forceinline__ bool probe_f32(const void* mask) {
  return *(const unsigned*)mask == 0x3F800000u;
}
__device__ __forceinline__ float ldin(const void* p, size_t i, bool f32) {
  return f32 ? ((const float*)p)[i] : (float)((const bf16*)p)[i];
}

// Fragment-major pack layout (global): for global row g (0..3071), col k (0..511):
//   chunk = g>>6 (64-row chunk, 65536 B each), r = g&63, c = k>>3 (16B block)
//   byte off = chunk*65536 + (c>>2)*4096 + (r>>4)*1024 + ((c&3)*16 + (r&15))*16 + (k&7)*2

// ---------- 1. prologue: pack_w (fragment-major) + biases + spike rotation ----------
// Hamilton block structure computed via bit tricks (NO runtime-indexed const
// arrays -> no scratch; rule #20): comp = ro^co; sign = bit (ro*4+co) of 0x284E.
__global__ __launch_bounds__(256) void prologue(
    const void* w0, const void* w1, const void* w2, const void* w3,
    const void* w4, const void* w5,
    const void* b0, const void* b1, const void* b2, const void* b3,
    const void* b4, const void* b5, const void* g_, const void* be,
    const void* q, const void* spike, const void* theta_logit, const void* mask,
    bf16* __restrict__ Wall, float* __restrict__ biasF,
    bf16* __restrict__ q_rot, float* __restrict__ qn) {
  bool f32 = probe_f32(mask);
  int blk = blockIdx.x, t = threadIdx.x;
  if (blk < 1536) {
    int E = blk * 1024 + t * 4;
    int g = E >> 9;            // global packed row 0..3071
    int wi = g >> 9;           // matrix index 0..5
    int o = g & 511;           // row within matrix
    int k0 = E & 511;          // col (multiple of 4)
    const void* src = wi == 0 ? w0 : wi == 1 ? w1 : wi == 2 ? w2 : wi == 3 ? w3 : wi == 4 ? w4 : w5;
    int ro = o >> 7, a = o & 127, co = k0 >> 7;
    int comp = ro ^ co;                                   // Hamilton component index
    float sgn = ((0x284Eu >> (ro * 4 + co)) & 1u) ? -1.0f : 1.0f;  // Hamilton sign
    bf16 ov[4];
    #pragma unroll
    for (int j = 0; j < 4; ++j) {
      int b2 = (k0 & 127) + j;
      ov[j] = (bf16)(ldin(src, comp * 16384 + a * 128 + b2, f32) * sgn);
    }
    int r = g & 63, c = k0 >> 3;
    size_t off = (size_t)(g >> 6) * 65536 + (size_t)((c >> 2) * 4096 + (r >> 4) * 1024
               + ((c & 3) * 16 + (r & 15)) * 16 + (k0 & 7) * 2);
    *(uint2*)((char*)Wall + off) = *(const uint2*)ov;
  } else if (blk < 1544) {
    int b = blk - 1536;
    const void* src = b == 0 ? b0 : b == 1 ? b1 : b == 2 ? b2 : b == 3 ? b3
                    : b == 4 ? b4 : b == 5 ? b5 : b == 6 ? g_ : be;
    biasF[b * 512 + t] = ldin(src, t, f32);
    biasF[b * 512 + 256 + t] = ldin(src, 256 + t, f32);
  } else {
    int row = (blk - 1544) * 2 + (t >> 7);
    int l = t & 127;
    float tl = ldin(theta_logit, 0, f32);
    float tmax = 1.5707963267948966f / (1.0f + __expf(-tl));
    float th = tmax * ldin(spike, row, f32);
    float c = cosf(th), s = sinf(th);
    size_t base = (size_t)row * 512;
    float a = ldin(q, base + l, f32), b = ldin(q, base + 128 + l, f32);
    float cc = ldin(q, base + 256 + l, f32), d = ldin(q, base + 384 + l, f32);
    float r0 = c * a - s * d;
    float r1 = c * b - s * cc;
    float r2 = c * cc + s * b;
    float r3 = c * d + s * a;
    bf16* orow = q_rot + base;
    orow[l] = (bf16)r0; orow[128 + l] = (bf16)r1; orow[256 + l] = (bf16)r2; orow[384 + l] = (bf16)r3;
    qn[(size_t)row * 128 + l] = r0 * r0 + r1 * r1 + r2 * r2 + r3 * r3;
  }
}

// ---------- staging: straight coalesced 64KB copy (Wall already fragment-major) ----------
__device__ __forceinline__ void stage_B64(const bf16* __restrict__ Bw, int n0, char* Bs, int t) {
  const char* src = (const char*)Bw + (size_t)(n0 >> 6) * 65536;
  #pragma unroll
  for (int i = 0; i < 16; ++i)
    *(uint4*)(Bs + t * 16 + i * 4096) = *(const uint4*)(src + t * 16 + i * 4096);
}

// ---------- 2. FUSED dist_h + gemm1 ----------
__global__ __launch_bounds__(256, 2) void gemm_dist(
    const bf16* __restrict__ A, const bf16* __restrict__ Bw,
    const float* __restrict__ bias0, const float* __restrict__ bias1,
    bf16* __restrict__ MQ,
    const float* __restrict__ qn, const void* anchors, const void* lsig,
    const void* mask, float* __restrict__ h_part, float* __restrict__ pd_part) {
  __shared__ char smem[77952];
  const int t = threadIdx.x;
  if (blockIdx.x >= 128) {
    char* Bs = smem;
    const int g = blockIdx.x - 128;
    const int wave = t >> 6, lane = t & 63;
    const int quad = lane >> 4, l16 = lane & 15;
    const int m0 = (g & 31) * 256, n0 = (g >> 5) * 64;
    stage_B64(Bw, n0, Bs, t);
    __syncthreads();
    const int mbase = m0 + wave * 64;
    f32x4 acc[4][4] = {};
    bf16x8 areg[2][4], breg[2][4];
    #pragma unroll
    for (int mt = 0; mt < 4; ++mt)
      areg[0][mt] = *(const bf16x8*)(A + (size_t)(mbase + mt * 16 + l16) * 512 + quad * 8);
    #pragma unroll
    for (int nt = 0; nt < 4; ++nt)
      breg[0][nt] = *(const bf16x8*)(Bs + nt * 1024 + lane * 16);
    #pragma unroll
    for (int kk = 0; kk < 16; ++kk) {
      const int cur = kk & 1, nxt = cur ^ 1;
      if (kk < 15) {
        const int k2 = (kk + 1) * 32;
        #pragma unroll
        for (int mt = 0; mt < 4; ++mt)
          areg[nxt][mt] = *(const bf16x8*)(A + (size_t)(mbase + mt * 16 + l16) * 512 + k2 + quad * 8);
        #pragma unroll
        for (int nt = 0; nt < 4; ++nt)
          breg[nxt][nt] = *(const bf16x8*)(Bs + (kk + 1) * 4096 + nt * 1024 + lane * 16);
      }
      #pragma unroll
      for (int mt = 0; mt < 4; ++mt)
        #pragma unroll
        for (int nt = 0; nt < 4; ++nt)
          acc[mt][nt] = __builtin_amdgcn_mfma_f32_16x16x32_bf16(areg[cur][mt], breg[cur][nt],
                                                                acc[mt][nt], 0, 0, 0);
    }
    #pragma unroll
    for (int nt = 0; nt < 4; ++nt) {
      int col = n0 + nt * 16 + l16;
      float bv = col < 512 ? bias0[col] : bias1[col - 512];
      #pragma unroll
      for (int mt = 0; mt < 4; ++mt) {
        int rb = mbase + mt * 16 + quad * 4;
        #pragma unroll
        for (int r = 0; r < 4; ++r)
          MQ[(size_t)(rb + r) * 1024 + col] = (bf16)(acc[mt][nt][r] + bv);
      }
    }
  } else {
    bool f32 = probe_f32(mask);
    bf16*  qr    = (bf16*)smem;                  // 65536 B
    float* an    = (float*)(smem + 65536);       // 8192 B
    float* sIncT = (float*)(smem + 73728);       // 4096 B  [nn][k] transposed
    float* rs    = (float*)(smem + 77824);       // 64 B
    float* pd    = (float*)(smem + 77888);       // 64 B
    int bb = blockIdx.x;
    int b = bb >> 4, nc = bb & 15;
    {
      const uint4* src = (const uint4*)((const bf16*)A + ((size_t)b * 1024 + nc * 64) * 512);
      uint4* dst = (uint4*)qr;
      #pragma unroll
      for (int i = 0; i < 16; ++i) dst[t + i * 256] = src[t + i * 256];
    }
    for (int i = t; i < 2048; i += 256) {
      int k = i >> 7, l = i & 127;
      float a0 = ldin(anchors, k * 512 + l, f32);
      float a1 = ldin(anchors, k * 512 + 128 + l, f32);
      float a2 = ldin(anchors, k * 512 + 256 + l, f32);
      float a3 = ldin(anchors, k * 512 + 384 + l, f32);
      an[i] = a0 * a0 + a1 * a1 + a2 * a2 + a3 * a3;
    }
    if (t < 16) {
      float ls = ldin(lsig, t, f32);
      float ssq = __expf(ls); ssq = fmaxf(ssq * ssq, 1e-6f);
      rs[t] = -1.0f / ssq;
      pd[t] = 0.0f;
    }
    __syncthreads();
    {
      int rl = t >> 2, part = t & 3;
      int n = nc * 64 + rl;
      const float* qrow = qn + ((size_t)b * 1024 + n) * 128 + part * 32;
      f32x4 q4[8];
      #pragma unroll
      for (int i = 0; i < 8; ++i) q4[i] = *(const f32x4*)(qrow + i * 4);
      float sc[16] = {};
      #pragma unroll
      for (int i = 0; i < 8; ++i) {
        #pragma unroll
        for (int k = 0; k < 16; ++k) {
          f32x4 av = *(const f32x4*)(an + k * 128 + part * 32 + i * 4);
          sc[k] += q4[i][0] * av[0] + q4[i][1] * av[1] + q4[i][2] * av[2] + q4[i][3] * av[3];
        }
      }
      #pragma unroll
      for (int k = 0; k < 16; ++k) {
        sc[k] += __shfl_xor(sc[k], 1, 64);
        sc[k] += __shfl_xor(sc[k], 2, 64);
      }
      if (part == 0) {
        float mval = ldin(mask, b * 1024 + n, f32);
        #pragma unroll
        for (int k = 0; k < 16; ++k) {
          float inc = __expf(sc[k] * rs[k]) * mval;
          sIncT[rl * 16 + k] = inc;           // transposed: [nn][k]
          atomicAdd(&pd[k], inc);
        }
      }
    }
    __syncthreads();
    {
      // thread t owns contiguous col pair (2t, 2t+1): one u32 LDS read per nn;
      // sIncT broadcast-read as 4x b128 per nn (was 16 scalar reads).
      float acc0[16] = {}, acc1[16] = {};
      for (int nn = 0; nn < 64; ++nn) {
        unsigned u = *(const unsigned*)(qr + nn * 512 + 2 * t);
        float v0 = bflo(u);
        float v1 = bfhi(u);
        f32x4 p0 = *(const f32x4*)(sIncT + nn * 16);
        f32x4 p1 = *(const f32x4*)(sIncT + nn * 16 + 4);
        f32x4 p2 = *(const f32x4*)(sIncT + nn * 16 + 8);
        f32x4 p3 = *(const f32x4*)(sIncT + nn * 16 + 12);
        #pragma unroll
        for (int j = 0; j < 4; ++j) {
          acc0[j]      += p0[j] * v0; acc1[j]      += p0[j] * v1;
          acc0[4 + j]  += p1[j] * v0; acc1[4 + j]  += p1[j] * v1;
          acc0[8 + j]  += p2[j] * v0; acc1[8 + j]  += p2[j] * v1;
          acc0[12 + j] += p3[j] * v0; acc1[12 + j] += p3[j] * v1;
        }
      }
      #pragma unroll
      for (int k = 0; k < 16; ++k) {
        size_t base = ((size_t)(b * 16 + k) * 16 + nc) * 512;
        float2 o2 = {acc0[k], acc1[k]};
        *(float2*)(h_part + base + 2 * t) = o2;
      }
    }
    if (t < 16) pd_part[((size_t)(b * 16 + t)) * 16 + nc] = pd[t];
  }
}

// ---------- partial row-dot against fragment-major packed W (4 of 16 col-chunks) ----------
__device__ __forceinline__ float dotW4(const char* WallB, int gRow, const float* xp512, int c4lo) {
  const char* p = WallB + (size_t)(gRow >> 6) * 65536
                + (size_t)(((gRow >> 4) & 3) * 1024 + (gRow & 15) * 16);
  float acc = 0.0f;
  #pragma unroll
  for (int c4 = c4lo; c4 < c4lo + 4; ++c4) {
    #pragma unroll
    for (int cl = 0; cl < 4; ++cl) {
      uint4 u = *(const uint4*)(p + c4 * 4096 + cl * 256);
      const float* xp = xp512 + c4 * 32 + cl * 8;
      acc += xp[0] * bflo(u.x) + xp[1] * bfhi(u.x)
           + xp[2] * bflo(u.y) + xp[3] * bfhi(u.y)
           + xp[4] * bflo(u.z) + xp[5] * bfhi(u.z)
           + xp[6] * bflo(u.w) + xp[7] * bfhi(u.w);
    }
  }
  return acc;
}

// ---------- 3a. reduce + aggr projection: grid 1024 (gy=bx>>7, row=bx&127) ----------
__global__ __launch_bounds__(256) void aggr_k(
    const float* __restrict__ h_part, const float* __restrict__ pd_part,
    const bf16* __restrict__ Wall, const float* __restrict__ biasF,
    float* __restrict__ h_aggr) {
  __shared__ float xs[512];
  const char* WallB = (const char*)Wall;
  const float* ba = biasF + 1536;
  const int gy = blockIdx.x >> 7, row = blockIdx.x & 127;
  const int t = threadIdx.x;
  float dsum = 0.0f;
  #pragma unroll
  for (int nc = 0; nc < 16; ++nc) dsum += pd_part[row * 16 + nc];
  float dinv = 1.0f / fmaxf(dsum, 1e-6f);
  #pragma unroll
  for (int j = 0; j < 2; ++j) {
    int d = j * 256 + t;
    float hv = 0.0f;
    #pragma unroll
    for (int nc = 0; nc < 16; ++nc) hv += h_part[(size_t)row * 8192 + nc * 512 + d];
    xs[d] = hv * dinv;
  }
  __syncthreads();
  const int o = gy * 64 + (t >> 2), part = t & 3;
  float acc = dotW4(WallB, 1536 + o, xs, part * 4);
  acc += __shfl_xor(acc, 1, 64);
  acc += __shfl_xor(acc, 2, 64);
  if (part == 0) h_aggr[(size_t)row * 512 + o] = acc + ba[o];
}

// ---------- 3b. K/V projections: grid 1024 (gy=bx>>7, row=bx&127) ----------
__global__ __launch_bounds__(256) void kv_k(
    const float* __restrict__ h_aggr, const bf16* __restrict__ Wall,
    const float* __restrict__ biasF,
    float* __restrict__ Kh, float* __restrict__ Vh) {
  __shared__ float ys[512];
  const char* WallB = (const char*)Wall;
  const float* bk = biasF + 2048;
  const float* bv = biasF + 2560;
  const int gy = blockIdx.x >> 7, row = blockIdx.x & 127;
  const int t = threadIdx.x;
  #pragma unroll
  for (int j = 0; j < 2; ++j) {
    int d = j * 256 + t;
    ys[d] = h_aggr[(size_t)row * 512 + d];
  }
  __syncthreads();
  const int o = gy * 64 + (t >> 2), part = t & 3;
  float ak = dotW4(WallB, 2048 + o, ys, part * 4);
  float av = dotW4(WallB, 2560 + o, ys, part * 4);
  ak += __shfl_xor(ak, 1, 64);
  ak += __shfl_xor(ak, 2, 64);
  av += __shfl_xor(av, 1, 64);
  av += __shfl_xor(av, 2, 64);
  if (part == 0) {
    Kh[(size_t)row * 512 + o] = ak + bk[o];
    Vh[(size_t)row * 512 + o] = av + bv[o];
  }
}

// ---------- 4. fused attention + gemm2(Wo) + residual + quaternion LN ----------
__global__ __launch_bounds__(256, 2) void attn_tail(
    const bf16* __restrict__ MQ, const float* __restrict__ Kh_g,
    const float* __restrict__ Vh_g, const bf16* __restrict__ Wall,
    const float* __restrict__ biasF, const void* q, const void* mask, void* out) {
  __shared__ float KV[8 * 1092];      // 34944 B; later aliased as 16KB A_lds
  __shared__ float P[16 * 132];       // 8448 B
  const bool f32 = probe_f32(mask);
  const int t = threadIdx.x;
  const int rowbase = blockIdx.x * 16;
  const int b = rowbase >> 10;
  for (int i = t; i < 8192; i += 256) {
    int k = i >> 9, d = i & 511, h = d >> 6, dd = d & 63;
    KV[h * 1092 + k * 68 + dd] = Kh_g[(size_t)b * 8192 + i];
  }
  __syncthreads();
  {
    const int r = t >> 4, h = (t >> 1) & 7, hf = t & 1;
    const int grow = rowbase + r;
    const uint4* qp = (const uint4*)(MQ + (size_t)grow * 1024 + 512 + h * 64 + hf * 32);
    float qv[32];
    #pragma unroll
    for (int i = 0; i < 4; ++i) {
      uint4 u = qp[i];
      qv[i * 8 + 0] = bflo(u.x); qv[i * 8 + 1] = bfhi(u.x);
      qv[i * 8 + 2] = bflo(u.y); qv[i * 8 + 3] = bfhi(u.y);
      qv[i * 8 + 4] = bflo(u.z); qv[i * 8 + 5] = bfhi(u.z);
      qv[i * 8 + 6] = bflo(u.w); qv[i * 8 + 7] = bfhi(u.w);
    }
    float sc[16];
    #pragma unroll
    for (int k = 0; k < 16; ++k) {
      float s = 0.0f;
      #pragma unroll
      for (int d4 = 0; d4 < 8; ++d4) {
        f32x4 kv = *(const f32x4*)(KV + h * 1092 + k * 68 + hf * 32 + d4 * 4);
        s += qv[d4 * 4 + 0] * kv[0] + qv[d4 * 4 + 1] * kv[1]
           + qv[d4 * 4 + 2] * kv[2] + qv[d4 * 4 + 3] * kv[3];
      }
      sc[k] = s;
    }
    #pragma unroll
    for (int k = 0; k < 16; ++k) sc[k] += __shfl_xor(sc[k], 1, 64);
    if (hf == 0) {
      #pragma unroll
      for (int k = 0; k < 16; ++k) sc[k] *= 0.125f;
      float m = sc[0];
      #pragma unroll
      for (int k = 1; k < 16; ++k) m = fmaxf(m, sc[k]);
      float ssum = 0.0f;
      #pragma unroll
      for (int k = 0; k < 16; ++k) { sc[k] = __expf(sc[k] - m); ssum += sc[k]; }
      float inv = 1.0f / ssum;
      #pragma unroll
      for (int k = 0; k < 16; ++k) P[r * 132 + h * 16 + k] = sc[k] * inv;
    }
  }
  __syncthreads();
  for (int i = t; i < 8192; i += 256) {
    int k = i >> 9, d = i & 511, h = d >> 6, dd = d & 63;
    KV[h * 1092 + k * 68 + dd] = Vh_g[(size_t)b * 8192 + i];
  }
  __syncthreads();
  float pv[8][4];
  {
    const int r = t >> 4, dg = t & 15;
    #pragma unroll
    for (int h = 0; h < 8; ++h) {
      float a0 = 0, a1 = 0, a2 = 0, a3 = 0;
      #pragma unroll
      for (int k = 0; k < 16; ++k) {
        float p = P[r * 132 + h * 16 + k];
        f32x4 va = *(const f32x4*)(KV + h * 1092 + k * 68 + dg * 4);
        a0 += p * va[0]; a1 += p * va[1]; a2 += p * va[2]; a3 += p * va[3];
      }
      pv[h][0] = a0; pv[h][1] = a1; pv[h][2] = a2; pv[h][3] = a3;
    }
  }
  __syncthreads();
  char* A_lds = (char*)KV;
  {
    const int r = t >> 4, dg = t & 15;
    #pragma unroll
    for (int h = 0; h < 8; ++h) {
      int c0 = h * 64 + dg * 4;
      int off = (c0 >> 5) * 1024 + ((c0 >> 3) & 3) * 256 + r * 16 + (c0 & 7) * 2;
      bf16 ov[4] = {(bf16)pv[h][0], (bf16)pv[h][1], (bf16)pv[h][2], (bf16)pv[h][3]};
      *(uint2*)(A_lds + off) = *(const uint2*)ov;
    }
  }
  __syncthreads();
  const int wave = t >> 6, lane = t & 63, quad = lane >> 4, l16 = lane & 15;
  const char* WallB = (const char*)Wall;
  f32x4 acc[8] = {};
  bf16x8 breg[2][8];
  bf16x8 areg[2];
  areg[0] = *(const bf16x8*)(A_lds + quad * 256 + l16 * 16);
  #pragma unroll
  for (int nt = 0; nt < 8; ++nt) {
    size_t cb = (size_t)(16 + wave * 2 + (nt >> 2)) * 65536;
    breg[0][nt] = *(const bf16x8*)(WallB + cb + (nt & 3) * 1024 + lane * 16);
  }
  #pragma unroll
  for (int kk = 0; kk < 16; ++kk) {
    const int cur = kk & 1, nxt = cur ^ 1;
    if (kk < 15) {
      areg[nxt] = *(const bf16x8*)(A_lds + (kk + 1) * 1024 + quad * 256 + l16 * 16);
      #pragma unroll
      for (int nt = 0; nt < 8; ++nt) {
        size_t cb = (size_t)(16 + wave * 2 + (nt >> 2)) * 65536;
        breg[nxt][nt] = *(const bf16x8*)(WallB + cb + (kk + 1) * 4096 + (nt & 3) * 1024 + lane * 16);
      }
    }
    #pragma unroll
    for (int nt = 0; nt < 8; ++nt)
      acc[nt] = __builtin_amdgcn_mfma_f32_16x16x32_bf16(areg[cur], breg[cur][nt], acc[nt], 0, 0, 0);
  }
  const float* biasO = biasF + 1024;
  const float* gamF = biasF + 3072;
  float xv[8][4];
  float s[4] = {0, 0, 0, 0}, s2[4] = {0, 0, 0, 0};
  #pragma unroll
  for (int nt = 0; nt < 8; ++nt) {
    int gcol = wave * 128 + nt * 16 + l16;
    float bo = biasO[gcol];
    #pragma unroll
    for (int reg = 0; reg < 4; ++reg) {
      int grow = rowbase + quad * 4 + reg;
      float qv = ldin(q, (size_t)grow * 512 + gcol, f32);
      float mp = (float)MQ[(size_t)grow * 1024 + gcol];
      float x = qv + mp + acc[nt][reg] + bo;
      xv[nt][reg] = x;
      s[reg] += x; s2[reg] += x * x;
    }
  }
  #pragma unroll
  for (int reg = 0; reg < 4; ++reg) {
    #pragma unroll
    for (int off = 1; off <= 8; off <<= 1) {
      s[reg]  += __shfl_xor(s[reg], off, 64);
      s2[reg] += __shfl_xor(s2[reg], off, 64);
    }
  }
  #pragma unroll
  for (int reg = 0; reg < 4; ++reg) {
    float m = s[reg] * (1.0f / 128.0f);
    float rinv = rsqrtf(s2[reg] * (1.0f / 128.0f) - m * m + 1e-5f);
    int grow = rowbase + quad * 4 + reg;
    #pragma unroll
    for (int nt = 0; nt < 8; ++nt) {
      int gcol = wave * 128 + nt * 16 + l16;
      float y = (xv[nt][reg] - m) * rinv * gamF[gcol] + gamF[512 + gcol];
      if (f32) ((float*)out)[(size_t)grow * 512 + gcol] = y;
      else     ((bf16*)out)[(size_t)grow * 512 + gcol] = (bf16)y;
    }
  }
}

// ---------- launch ----------
extern "C" void kernel_launch(void* const* d_in, const int* in_sizes, int n_in,
                              void* d_out, int out_size, void* d_ws, size_t ws_size,
                              hipStream_t stream) {
  (void)in_sizes; (void)n_in; (void)out_size; (void)ws_size;
  const void* q      = d_in[0];
  const void* spike  = d_in[1];
  const void* mask   = d_in[2];
  const void* tl     = d_in[3];
  const void* w_prim = d_in[4];
  const void* b_prim = d_in[5];
  const void* anchors= d_in[6];
  const void* lsig   = d_in[7];
  const void* w_aggr = d_in[8];
  const void* b_aggr = d_in[9];
  const void* w_q    = d_in[10];
  const void* b_q    = d_in[11];
  const void* w_k    = d_in[12];
  const void* b_k    = d_in[13];
  const void* w_v    = d_in[14];
  const void* b_v    = d_in[15];
  const void* w_o    = d_in[16];
  const void* b_o    = d_in[17];
  const void* gam    = d_in[18];
  const void* bet    = d_in[19];

  char* ws = (char*)d_ws;
  bf16*  Wall   = (bf16*)(ws + 0);            // 3,145,728 (fragment-major packed)
  bf16*  q_rot  = (bf16*)(ws + 3145728);      // 8,388,608
  float* qn     = (float*)(ws + 11534336);    // 4,194,304
  bf16*  MQ     = (bf16*)(ws + 15728640);     // 16,777,216
  float* h_part = (float*)(ws + 32505856);    // 4,194,304
  float* pd_part= (float*)(ws + 36700160);    // 8,192
  float* Kh     = (float*)(ws + 36708352);    // 262,144
  float* Vh     = (float*)(ws + 36970496);    // 262,144
  float* biasF  = (float*)(ws + 37232640);    // 16,384
  float* h_aggr = (float*)(ws + 37249024);    // 262,144 (end 37,511,168)

  prologue<<<5640, 256, 0, stream>>>(w_prim, w_q, w_o, w_aggr, w_k, w_v,
                                     b_prim, b_q, b_o, b_aggr, b_k, b_v, gam, bet,
                                     q, spike, tl, mask, Wall, biasF, q_rot, qn);
  gemm_dist<<<640, 256, 0, stream>>>(q_rot, Wall, biasF + 0, biasF + 512, MQ,
                                     qn, anchors, lsig, mask, h_part, pd_part);
  aggr_k<<<1024, 256, 0, stream>>>(h_part, pd_part, Wall, biasF, h_aggr);
  kv_k<<<1024, 256, 0, stream>>>(h_aggr, Wall, biasF, Kh, Vh);
  attn_tail<<<512, 256, 0, stream>>>(MQ, Kh, Vh, Wall, biasF, q, mask, d_out);
}